// Round 1
// baseline (1135.573 us; speedup 1.0000x reference)
//
#include <hip/hip_runtime.h>
#include <hip/hip_bf16.h>

// ---------------- graph preprocessing ----------------

__global__ void k_deg(const int* __restrict__ dst, int* __restrict__ deg, int E) {
    int i = blockIdx.x * blockDim.x + threadIdx.x;
    if (i < E) atomicAdd(&deg[dst[i]], 1);
}

__global__ void k_dinv(const int* __restrict__ deg, float* __restrict__ dinv, int N) {
    int i = blockIdx.x * blockDim.x + threadIdx.x;
    if (i < N) dinv[i] = rsqrtf((float)(deg[i] + 1));  // +1 = self-loop
}

// single-block exclusive scan of deg -> rowptr[0..N]; also copies to cursor
__global__ void k_scan(const int* __restrict__ deg, int* __restrict__ rowptr,
                       int* __restrict__ cursor, int N) {
    __shared__ int ssum[256];
    int t = threadIdx.x;
    int chunk = (N + 255) / 256;
    int lo = t * chunk;
    int hi = min(lo + chunk, N);
    int s = 0;
    for (int i = lo; i < hi; i++) s += deg[i];
    ssum[t] = s;
    __syncthreads();
    if (t == 0) {
        int acc = 0;
        for (int i = 0; i < 256; i++) { int v = ssum[i]; ssum[i] = acc; acc += v; }
    }
    __syncthreads();
    int off = ssum[t];
    for (int i = lo; i < hi; i++) {
        rowptr[i] = off;
        cursor[i] = off;
        off += deg[i];
    }
    if (hi == N) rowptr[N] = off;  // all qualifying threads write the same total
}

__global__ void k_fill(const int* __restrict__ src, const int* __restrict__ dst,
                       int* __restrict__ cursor, int* __restrict__ csr, int E) {
    int i = blockIdx.x * blockDim.x + threadIdx.x;
    if (i < E) {
        int d = dst[i];
        int pos = atomicAdd(&cursor[d], 1);
        csr[pos] = src[i];
    }
}

// ---------------- GEMM: C[M x 128] = A[M x 128] @ W[128 x 128] ----------------
// block 256 threads, 128 rows/block, 8x8 register tile per thread

__global__ __launch_bounds__(256) void k_gemm128(const float* __restrict__ A,
                                                 const float* __restrict__ W,
                                                 float* __restrict__ C, int M) {
    __shared__ float As[128][20];   // padded: stride 20 floats (80B, float4-alignable)
    __shared__ float Ws[16][128];
    int t = threadIdx.x;
    int tx = t & 15;    // col group: cols tx + 16*j
    int ty = t >> 4;    // row group: rows ty + 16*i
    int row0 = blockIdx.x * 128;

    float acc[8][8];
#pragma unroll
    for (int i = 0; i < 8; i++)
#pragma unroll
        for (int j = 0; j < 8; j++) acc[i][j] = 0.f;

    for (int k0 = 0; k0 < 128; k0 += 16) {
        // stage A tile: 128 rows x 16 k = 512 float4
#pragma unroll
        for (int f = t; f < 512; f += 256) {
            int r = f >> 2, q = f & 3;
            float4 v = make_float4(0.f, 0.f, 0.f, 0.f);
            int row = row0 + r;
            if (row < M) v = *(const float4*)(A + (size_t)row * 128 + k0 + q * 4);
            *(float4*)&As[r][q * 4] = v;
        }
        // stage W tile: 16 x 128 = 512 float4
#pragma unroll
        for (int f = t; f < 512; f += 256) {
            int kk = f >> 5, q = f & 31;
            *(float4*)&Ws[kk][q * 4] = *(const float4*)(W + (size_t)(k0 + kk) * 128 + q * 4);
        }
        __syncthreads();
#pragma unroll
        for (int kk = 0; kk < 16; kk++) {
            float a[8], w[8];
#pragma unroll
            for (int i = 0; i < 8; i++) a[i] = As[ty + 16 * i][kk];
#pragma unroll
            for (int j = 0; j < 8; j++) w[j] = Ws[kk][tx + 16 * j];
#pragma unroll
            for (int i = 0; i < 8; i++)
#pragma unroll
                for (int j = 0; j < 8; j++) acc[i][j] += a[i] * w[j];
        }
        __syncthreads();
    }
#pragma unroll
    for (int i = 0; i < 8; i++) {
        int row = row0 + ty + 16 * i;
        if (row < M) {
#pragma unroll
            for (int j = 0; j < 8; j++) C[(size_t)row * 128 + tx + 16 * j] = acc[i][j];
        }
    }
}

// ---------------- GEMM: C[M x 40] = A[M x 128] @ W[128 x 40] ----------------
// block 256 threads, 64 rows/block, 10 cols per thread

__global__ __launch_bounds__(256) void k_gemm40(const float* __restrict__ A,
                                                const float* __restrict__ W,
                                                float* __restrict__ C, int M) {
    __shared__ float As[64][132];   // pad 128->132 to break bank conflicts
    __shared__ float Ws[128][40];
    int t = threadIdx.x;
    int r = t >> 2;       // 0..63
    int c0 = t & 3;       // cols c0 + 4*j, j<10
    int row0 = blockIdx.x * 64;

    // stage W (full 128x40): 1280 float4
    float* wflat = &Ws[0][0];
#pragma unroll
    for (int f = t; f < 1280; f += 256)
        *(float4*)&wflat[f * 4] = *(const float4*)(W + (size_t)f * 4);
    // stage A tile: 64 x 128 = 2048 float4
#pragma unroll
    for (int f = t; f < 2048; f += 256) {
        int rr = f >> 5, q = f & 31;
        float4 v = make_float4(0.f, 0.f, 0.f, 0.f);
        int row = row0 + rr;
        if (row < M) v = *(const float4*)(A + (size_t)row * 128 + q * 4);
        *(float4*)&As[rr][q * 4] = v;
    }
    __syncthreads();

    float acc[10];
#pragma unroll
    for (int j = 0; j < 10; j++) acc[j] = 0.f;
    for (int k = 0; k < 128; k++) {
        float a = As[r][k];
#pragma unroll
        for (int j = 0; j < 10; j++) acc[j] += a * Ws[k][c0 + 4 * j];
    }
    int row = row0 + r;
    if (row < M) {
#pragma unroll
        for (int j = 0; j < 10; j++) C[(size_t)row * 40 + c0 + 4 * j] = acc[j];
    }
}

// ---------------- aggregation: out[d] = dinv[d]*(sum h[s]*dinv[s] + h[d]*dinv[d]) + b ----------------

__global__ void k_agg128(const float* __restrict__ h, const float* __restrict__ dinv,
                         const int* __restrict__ rowptr, const int* __restrict__ csr,
                         const float* __restrict__ bias, float* __restrict__ out,
                         int relu) {
    int node = blockIdx.x;
    int j = threadIdx.x;  // 128
    float dn = dinv[node];
    float acc = h[(size_t)node * 128 + j] * dn;  // self-loop term (outer *dn applied below)
    int e0 = rowptr[node], e1 = rowptr[node + 1];
    for (int e = e0; e < e1; e++) {
        int s = csr[e];
        acc += h[(size_t)s * 128 + j] * dinv[s];
    }
    float v = acc * dn + bias[j];
    if (relu) v = fmaxf(v, 0.f);
    out[(size_t)node * 128 + j] = v;
}

__global__ void k_agg40(const float* __restrict__ h, const float* __restrict__ dinv,
                        const int* __restrict__ rowptr, const int* __restrict__ csr,
                        const float* __restrict__ bias, float* __restrict__ out) {
    int node = blockIdx.x;
    int j = threadIdx.x;  // 64, lanes >= 40 idle
    if (j >= 40) return;
    float dn = dinv[node];
    float acc = h[(size_t)node * 40 + j] * dn;
    int e0 = rowptr[node], e1 = rowptr[node + 1];
    for (int e = e0; e < e1; e++) {
        int s = csr[e];
        acc += h[(size_t)s * 40 + j] * dinv[s];
    }
    out[(size_t)node * 40 + j] = acc * dn + bias[j];
}

// ---------------- launch ----------------

extern "C" void kernel_launch(void* const* d_in, const int* in_sizes, int n_in,
                              void* d_out, int out_size, void* d_ws, size_t ws_size,
                              hipStream_t stream) {
    const float* x  = (const float*)d_in[0];
    const int* eidx = (const int*)d_in[1];
    const float* W1 = (const float*)d_in[2];
    const float* b1 = (const float*)d_in[3];
    const float* Wm = (const float*)d_in[4];
    const float* bm = (const float*)d_in[5];
    const float* W2 = (const float*)d_in[6];
    const float* b2 = (const float*)d_in[7];
    float* out = (float*)d_out;

    int N = in_sizes[0] / 128;
    int E = in_sizes[1] / 2;
    const int* src = eidx;
    const int* dst = eidx + E;

    char* ws = (char*)d_ws;
    size_t off = 0;
    auto alloc = [&](size_t bytes) -> void* {
        void* p = ws + off;
        off += (bytes + 255) & ~(size_t)255;
        return p;
    };
    int*   deg    = (int*)alloc((size_t)N * 4);
    float* dinv   = (float*)alloc((size_t)N * 4);
    int*   rowptr = (int*)alloc(((size_t)N + 1) * 4);
    int*   cursor = (int*)alloc(((size_t)N + 1) * 4);
    int*   csr    = (int*)alloc((size_t)E * 4);
    float* bufA   = (float*)alloc((size_t)N * 128 * 4);
    float* bufB   = (float*)alloc((size_t)N * 128 * 4);

    hipMemsetAsync(deg, 0, (size_t)N * 4, stream);
    k_deg<<<(E + 255) / 256, 256, 0, stream>>>(dst, deg, E);
    k_dinv<<<(N + 255) / 256, 256, 0, stream>>>(deg, dinv, N);
    k_scan<<<1, 256, 0, stream>>>(deg, rowptr, cursor, N);
    k_fill<<<(E + 255) / 256, 256, 0, stream>>>(src, dst, cursor, csr, E);

    // layer 1: h1 = relu(agg(x @ W1) + b1)
    k_gemm128<<<(N + 127) / 128, 256, 0, stream>>>(x, W1, bufA, N);
    k_agg128<<<N, 128, 0, stream>>>(bufA, dinv, rowptr, csr, b1, bufB, 1);
    // layer 2: h2 = relu(agg(h1 @ Wm) + bm)
    k_gemm128<<<(N + 127) / 128, 256, 0, stream>>>(bufB, Wm, bufA, N);
    k_agg128<<<N, 128, 0, stream>>>(bufA, dinv, rowptr, csr, bm, bufB, 1);
    // layer 3: out = agg(h2 @ W2) + b2
    k_gemm40<<<(N + 63) / 64, 256, 0, stream>>>(bufB, W2, bufA, N);
    k_agg40<<<N, 64, 0, stream>>>(bufA, dinv, rowptr, csr, b2, out);
}

// Round 2
// 914.956 us; speedup vs baseline: 1.2411x; 1.2411x over previous
//
#include <hip/hip_runtime.h>
#include <hip/hip_bf16.h>

// ---------------- graph preprocessing ----------------

__global__ void k_deg(const int* __restrict__ dst, int* __restrict__ deg, int E) {
    int i = blockIdx.x * blockDim.x + threadIdx.x;
    if (i < E) atomicAdd(&deg[dst[i]], 1);
}

__global__ void k_dinv(const int* __restrict__ deg, float* __restrict__ dinv, int N) {
    int i = blockIdx.x * blockDim.x + threadIdx.x;
    if (i < N) dinv[i] = rsqrtf((float)(deg[i] + 1));  // +1 = self-loop
}

// ---- 3-phase exclusive scan of deg -> rowptr[0..N] (+ cursor copy) ----
// phase 1: per-block partial sums (256 blocks)
__global__ void k_scan_p1(const int* __restrict__ deg, int* __restrict__ bsum, int N) {
    __shared__ int red[256];
    int chunk = (N + 255) / 256;
    int lo = blockIdx.x * chunk;
    int hi = min(lo + chunk, N);
    int s = 0;
    for (int i = lo + (int)threadIdx.x; i < hi; i += 256) s += deg[i];
    red[threadIdx.x] = s;
    __syncthreads();
    for (int d = 128; d > 0; d >>= 1) {
        if ((int)threadIdx.x < d) red[threadIdx.x] += red[threadIdx.x + d];
        __syncthreads();
    }
    if (threadIdx.x == 0) bsum[blockIdx.x] = red[0];
}

// phase 2: exclusive scan of the 256 block sums (1 block — tiny)
__global__ void k_scan_p2(int* __restrict__ bsum) {
    __shared__ int s[256];
    int t = threadIdx.x;
    s[t] = bsum[t];
    __syncthreads();
    for (int d = 1; d < 256; d <<= 1) {
        int u = (t >= d) ? s[t - d] : 0;
        __syncthreads();
        if (t >= d) s[t] += u;
        __syncthreads();
    }
    bsum[t] = (t == 0) ? 0 : s[t - 1];
}

// phase 3: re-scan each chunk with block offset (256 blocks)
__global__ void k_scan_p3(const int* __restrict__ deg, const int* __restrict__ bsum,
                          int* __restrict__ rowptr, int* __restrict__ cursor, int N) {
    __shared__ int s[256];
    __shared__ int carry;
    int chunk = (N + 255) / 256;
    int lo = blockIdx.x * chunk;
    int hi = min(lo + chunk, N);
    int t = threadIdx.x;
    if (t == 0) carry = bsum[blockIdx.x];
    __syncthreads();
    for (int base = lo; base < hi; base += 256) {
        int i = base + t;
        int v = (i < hi) ? deg[i] : 0;
        s[t] = v;
        __syncthreads();
        for (int d = 1; d < 256; d <<= 1) {
            int u = (t >= d) ? s[t - d] : 0;
            __syncthreads();
            if (t >= d) s[t] += u;
            __syncthreads();
        }
        int excl = carry + ((t == 0) ? 0 : s[t - 1]);
        if (i < hi) { rowptr[i] = excl; cursor[i] = excl; }
        __syncthreads();               // everyone reads carry before thread 0 bumps it
        if (t == 0) carry += s[255];
        __syncthreads();
    }
    if (blockIdx.x == gridDim.x - 1 && t == 0) rowptr[N] = carry;  // = total edge count
}

__global__ void k_fill(const int* __restrict__ src, const int* __restrict__ dst,
                       int* __restrict__ cursor, int* __restrict__ csr, int E) {
    int i = blockIdx.x * blockDim.x + threadIdx.x;
    if (i < E) {
        int d = dst[i];
        int pos = atomicAdd(&cursor[d], 1);
        csr[pos] = src[i];
    }
}

// ---------------- GEMM: C[M x 128] = A[M x 128] @ W[128 x 128] ----------------
// block 256 threads, 128 rows/block, 8x8 register tile per thread

__global__ __launch_bounds__(256) void k_gemm128(const float* __restrict__ A,
                                                 const float* __restrict__ W,
                                                 float* __restrict__ C, int M) {
    __shared__ float As[128][20];   // padded: stride 20 floats (80B, float4-alignable)
    __shared__ float Ws[16][128];
    int t = threadIdx.x;
    int tx = t & 15;    // col group: cols tx + 16*j
    int ty = t >> 4;    // row group: rows ty + 16*i
    int row0 = blockIdx.x * 128;

    float acc[8][8];
#pragma unroll
    for (int i = 0; i < 8; i++)
#pragma unroll
        for (int j = 0; j < 8; j++) acc[i][j] = 0.f;

    for (int k0 = 0; k0 < 128; k0 += 16) {
        // stage A tile: 128 rows x 16 k = 512 float4
#pragma unroll
        for (int f = t; f < 512; f += 256) {
            int r = f >> 2, q = f & 3;
            float4 v = make_float4(0.f, 0.f, 0.f, 0.f);
            int row = row0 + r;
            if (row < M) v = *(const float4*)(A + (size_t)row * 128 + k0 + q * 4);
            *(float4*)&As[r][q * 4] = v;
        }
        // stage W tile: 16 x 128 = 512 float4
#pragma unroll
        for (int f = t; f < 512; f += 256) {
            int kk = f >> 5, q = f & 31;
            *(float4*)&Ws[kk][q * 4] = *(const float4*)(W + (size_t)(k0 + kk) * 128 + q * 4);
        }
        __syncthreads();
#pragma unroll
        for (int kk = 0; kk < 16; kk++) {
            float a[8], w[8];
#pragma unroll
            for (int i = 0; i < 8; i++) a[i] = As[ty + 16 * i][kk];
#pragma unroll
            for (int j = 0; j < 8; j++) w[j] = Ws[kk][tx + 16 * j];
#pragma unroll
            for (int i = 0; i < 8; i++)
#pragma unroll
                for (int j = 0; j < 8; j++) acc[i][j] += a[i] * w[j];
        }
        __syncthreads();
    }
#pragma unroll
    for (int i = 0; i < 8; i++) {
        int row = row0 + ty + 16 * i;
        if (row < M) {
#pragma unroll
            for (int j = 0; j < 8; j++) C[(size_t)row * 128 + tx + 16 * j] = acc[i][j];
        }
    }
}

// ---------------- GEMM: C[M x 40] = A[M x 128] @ W[128 x 40] ----------------
// block 256 threads, 64 rows/block, 10 cols per thread

__global__ __launch_bounds__(256) void k_gemm40(const float* __restrict__ A,
                                                const float* __restrict__ W,
                                                float* __restrict__ C, int M) {
    __shared__ float As[64][132];   // pad 128->132 to break bank conflicts
    __shared__ float Ws[128][40];
    int t = threadIdx.x;
    int r = t >> 2;       // 0..63
    int c0 = t & 3;       // cols c0 + 4*j, j<10
    int row0 = blockIdx.x * 64;

    // stage W (full 128x40): 1280 float4
    float* wflat = &Ws[0][0];
#pragma unroll
    for (int f = t; f < 1280; f += 256)
        *(float4*)&wflat[f * 4] = *(const float4*)(W + (size_t)f * 4);
    // stage A tile: 64 x 128 = 2048 float4
#pragma unroll
    for (int f = t; f < 2048; f += 256) {
        int rr = f >> 5, q = f & 31;
        float4 v = make_float4(0.f, 0.f, 0.f, 0.f);
        int row = row0 + rr;
        if (row < M) v = *(const float4*)(A + (size_t)row * 128 + q * 4);
        *(float4*)&As[rr][q * 4] = v;
    }
    __syncthreads();

    float acc[10];
#pragma unroll
    for (int j = 0; j < 10; j++) acc[j] = 0.f;
    for (int k = 0; k < 128; k++) {
        float a = As[r][k];
#pragma unroll
        for (int j = 0; j < 10; j++) acc[j] += a * Ws[k][c0 + 4 * j];
    }
    int row = row0 + r;
    if (row < M) {
#pragma unroll
        for (int j = 0; j < 10; j++) C[(size_t)row * 40 + c0 + 4 * j] = acc[j];
    }
}

// ---------------- aggregation: out[d] = dinv[d]*(sum h[s]*dinv[s] + h[d]*dinv[d]) + b ----------------

__global__ void k_agg128(const float* __restrict__ h, const float* __restrict__ dinv,
                         const int* __restrict__ rowptr, const int* __restrict__ csr,
                         const float* __restrict__ bias, float* __restrict__ out,
                         int relu) {
    int node = blockIdx.x;
    int j = threadIdx.x;  // 128
    float dn = dinv[node];
    float acc = h[(size_t)node * 128 + j] * dn;  // self-loop term (outer *dn applied below)
    int e0 = rowptr[node], e1 = rowptr[node + 1];
    for (int e = e0; e < e1; e++) {
        int s = csr[e];
        acc += h[(size_t)s * 128 + j] * dinv[s];
    }
    float v = acc * dn + bias[j];
    if (relu) v = fmaxf(v, 0.f);
    out[(size_t)node * 128 + j] = v;
}

__global__ void k_agg40(const float* __restrict__ h, const float* __restrict__ dinv,
                        const int* __restrict__ rowptr, const int* __restrict__ csr,
                        const float* __restrict__ bias, float* __restrict__ out) {
    int node = blockIdx.x;
    int j = threadIdx.x;  // 64, lanes >= 40 idle
    if (j >= 40) return;
    float dn = dinv[node];
    float acc = h[(size_t)node * 40 + j] * dn;
    int e0 = rowptr[node], e1 = rowptr[node + 1];
    for (int e = e0; e < e1; e++) {
        int s = csr[e];
        acc += h[(size_t)s * 40 + j] * dinv[s];
    }
    out[(size_t)node * 40 + j] = acc * dn + bias[j];
}

// ---------------- launch ----------------

extern "C" void kernel_launch(void* const* d_in, const int* in_sizes, int n_in,
                              void* d_out, int out_size, void* d_ws, size_t ws_size,
                              hipStream_t stream) {
    const float* x  = (const float*)d_in[0];
    const int* eidx = (const int*)d_in[1];
    const float* W1 = (const float*)d_in[2];
    const float* b1 = (const float*)d_in[3];
    const float* Wm = (const float*)d_in[4];
    const float* bm = (const float*)d_in[5];
    const float* W2 = (const float*)d_in[6];
    const float* b2 = (const float*)d_in[7];
    float* out = (float*)d_out;

    int N = in_sizes[0] / 128;
    int E = in_sizes[1] / 2;
    const int* src = eidx;
    const int* dst = eidx + E;

    char* ws = (char*)d_ws;
    size_t off = 0;
    auto alloc = [&](size_t bytes) -> void* {
        void* p = ws + off;
        off += (bytes + 255) & ~(size_t)255;
        return p;
    };
    int*   deg    = (int*)alloc((size_t)N * 4);
    float* dinv   = (float*)alloc((size_t)N * 4);
    int*   rowptr = (int*)alloc(((size_t)N + 1) * 4);
    int*   cursor = (int*)alloc(((size_t)N + 1) * 4);
    int*   csr    = (int*)alloc((size_t)E * 4);
    int*   bsum   = (int*)alloc(256 * 4);
    float* bufA   = (float*)alloc((size_t)N * 128 * 4);
    float* bufB   = (float*)alloc((size_t)N * 128 * 4);

    hipMemsetAsync(deg, 0, (size_t)N * 4, stream);
    k_deg<<<(E + 255) / 256, 256, 0, stream>>>(dst, deg, E);
    k_dinv<<<(N + 255) / 256, 256, 0, stream>>>(deg, dinv, N);
    k_scan_p1<<<256, 256, 0, stream>>>(deg, bsum, N);
    k_scan_p2<<<1, 256, 0, stream>>>(bsum);
    k_scan_p3<<<256, 256, 0, stream>>>(deg, bsum, rowptr, cursor, N);
    k_fill<<<(E + 255) / 256, 256, 0, stream>>>(src, dst, cursor, csr, E);

    // layer 1: h1 = relu(agg(x @ W1) + b1)
    k_gemm128<<<(N + 127) / 128, 256, 0, stream>>>(x, W1, bufA, N);
    k_agg128<<<N, 128, 0, stream>>>(bufA, dinv, rowptr, csr, b1, bufB, 1);
    // layer 2: h2 = relu(agg(h1 @ Wm) + bm)
    k_gemm128<<<(N + 127) / 128, 256, 0, stream>>>(bufB, Wm, bufA, N);
    k_agg128<<<N, 128, 0, stream>>>(bufA, dinv, rowptr, csr, bm, bufB, 1);
    // layer 3: out = agg(h2 @ W2) + b2
    k_gemm40<<<(N + 63) / 64, 256, 0, stream>>>(bufB, W2, bufA, N);
    k_agg40<<<N, 64, 0, stream>>>(bufA, dinv, rowptr, csr, b2, out);
}

// Round 3
// 781.847 us; speedup vs baseline: 1.4524x; 1.1702x over previous
//
#include <hip/hip_runtime.h>
#include <hip/hip_bf16.h>

// ---------------- graph preprocessing ----------------

__global__ void k_deg(const int* __restrict__ dst, int* __restrict__ deg, int E) {
    int i = blockIdx.x * blockDim.x + threadIdx.x;
    if (i < E) atomicAdd(&deg[dst[i]], 1);
}

__global__ void k_dinv(const int* __restrict__ deg, float* __restrict__ dinv, int N) {
    int i = blockIdx.x * blockDim.x + threadIdx.x;
    if (i < N) dinv[i] = rsqrtf((float)(deg[i] + 1));  // +1 = self-loop
}

// ---- 3-phase exclusive scan of deg -> rowptr[0..N] (+ cursor copy) ----
__global__ void k_scan_p1(const int* __restrict__ deg, int* __restrict__ bsum, int N) {
    __shared__ int red[256];
    int chunk = (N + 255) / 256;
    int lo = blockIdx.x * chunk;
    int hi = min(lo + chunk, N);
    int s = 0;
    for (int i = lo + (int)threadIdx.x; i < hi; i += 256) s += deg[i];
    red[threadIdx.x] = s;
    __syncthreads();
    for (int d = 128; d > 0; d >>= 1) {
        if ((int)threadIdx.x < d) red[threadIdx.x] += red[threadIdx.x + d];
        __syncthreads();
    }
    if (threadIdx.x == 0) bsum[blockIdx.x] = red[0];
}

__global__ void k_scan_p2(int* __restrict__ bsum) {
    __shared__ int s[256];
    int t = threadIdx.x;
    s[t] = bsum[t];
    __syncthreads();
    for (int d = 1; d < 256; d <<= 1) {
        int u = (t >= d) ? s[t - d] : 0;
        __syncthreads();
        if (t >= d) s[t] += u;
        __syncthreads();
    }
    bsum[t] = (t == 0) ? 0 : s[t - 1];
}

__global__ void k_scan_p3(const int* __restrict__ deg, const int* __restrict__ bsum,
                          int* __restrict__ rowptr, int* __restrict__ cursor, int N) {
    __shared__ int s[256];
    __shared__ int carry;
    int chunk = (N + 255) / 256;
    int lo = blockIdx.x * chunk;
    int hi = min(lo + chunk, N);
    int t = threadIdx.x;
    if (t == 0) carry = bsum[blockIdx.x];
    __syncthreads();
    for (int base = lo; base < hi; base += 256) {
        int i = base + t;
        int v = (i < hi) ? deg[i] : 0;
        s[t] = v;
        __syncthreads();
        for (int d = 1; d < 256; d <<= 1) {
            int u = (t >= d) ? s[t - d] : 0;
            __syncthreads();
            if (t >= d) s[t] += u;
            __syncthreads();
        }
        int excl = carry + ((t == 0) ? 0 : s[t - 1]);
        if (i < hi) { rowptr[i] = excl; cursor[i] = excl; }
        __syncthreads();
        if (t == 0) carry += s[255];
        __syncthreads();
    }
    if (blockIdx.x == gridDim.x - 1 && t == 0) rowptr[N] = carry;
}

__global__ void k_fill(const int* __restrict__ src, const int* __restrict__ dst,
                       int* __restrict__ cursor, int* __restrict__ csr, int E) {
    int i = blockIdx.x * blockDim.x + threadIdx.x;
    if (i < E) {
        int d = dst[i];
        int pos = atomicAdd(&cursor[d], 1);
        csr[pos] = src[i];
    }
}

// ---------------- GEMM: C[M x 128] = A[M x 128] @ W[128 x 128] ----------------

__global__ __launch_bounds__(256) void k_gemm128(const float* __restrict__ A,
                                                 const float* __restrict__ W,
                                                 float* __restrict__ C, int M) {
    __shared__ float As[128][20];
    __shared__ float Ws[16][128];
    int t = threadIdx.x;
    int tx = t & 15;
    int ty = t >> 4;
    int row0 = blockIdx.x * 128;

    float acc[8][8];
#pragma unroll
    for (int i = 0; i < 8; i++)
#pragma unroll
        for (int j = 0; j < 8; j++) acc[i][j] = 0.f;

    for (int k0 = 0; k0 < 128; k0 += 16) {
#pragma unroll
        for (int f = t; f < 512; f += 256) {
            int r = f >> 2, q = f & 3;
            float4 v = make_float4(0.f, 0.f, 0.f, 0.f);
            int row = row0 + r;
            if (row < M) v = *(const float4*)(A + (size_t)row * 128 + k0 + q * 4);
            *(float4*)&As[r][q * 4] = v;
        }
#pragma unroll
        for (int f = t; f < 512; f += 256) {
            int kk = f >> 5, q = f & 31;
            *(float4*)&Ws[kk][q * 4] = *(const float4*)(W + (size_t)(k0 + kk) * 128 + q * 4);
        }
        __syncthreads();
#pragma unroll
        for (int kk = 0; kk < 16; kk++) {
            float a[8], w[8];
#pragma unroll
            for (int i = 0; i < 8; i++) a[i] = As[ty + 16 * i][kk];
#pragma unroll
            for (int j = 0; j < 8; j++) w[j] = Ws[kk][tx + 16 * j];
#pragma unroll
            for (int i = 0; i < 8; i++)
#pragma unroll
                for (int j = 0; j < 8; j++) acc[i][j] += a[i] * w[j];
        }
        __syncthreads();
    }
#pragma unroll
    for (int i = 0; i < 8; i++) {
        int row = row0 + ty + 16 * i;
        if (row < M) {
#pragma unroll
            for (int j = 0; j < 8; j++) C[(size_t)row * 128 + tx + 16 * j] = acc[i][j];
        }
    }
}

// ---------------- GEMM: C[M x 40] = A[M x 128] @ W[128 x 40] ----------------

__global__ __launch_bounds__(256) void k_gemm40(const float* __restrict__ A,
                                                const float* __restrict__ W,
                                                float* __restrict__ C, int M) {
    __shared__ float As[64][132];
    __shared__ float Ws[128][40];
    int t = threadIdx.x;
    int r = t >> 2;
    int c0 = t & 3;
    int row0 = blockIdx.x * 64;

    float* wflat = &Ws[0][0];
#pragma unroll
    for (int f = t; f < 1280; f += 256)
        *(float4*)&wflat[f * 4] = *(const float4*)(W + (size_t)f * 4);
#pragma unroll
    for (int f = t; f < 2048; f += 256) {
        int rr = f >> 5, q = f & 31;
        float4 v = make_float4(0.f, 0.f, 0.f, 0.f);
        int row = row0 + rr;
        if (row < M) v = *(const float4*)(A + (size_t)row * 128 + q * 4);
        *(float4*)&As[rr][q * 4] = v;
    }
    __syncthreads();

    float acc[10];
#pragma unroll
    for (int j = 0; j < 10; j++) acc[j] = 0.f;
    for (int k = 0; k < 128; k++) {
        float a = As[r][k];
#pragma unroll
        for (int j = 0; j < 10; j++) acc[j] += a * Ws[k][c0 + 4 * j];
    }
    int row = row0 + r;
    if (row < M) {
#pragma unroll
        for (int j = 0; j < 10; j++) C[(size_t)row * 40 + c0 + 4 * j] = acc[j];
    }
}

// ---------------- aggregation ----------------
// out[d] = dinv[d]*(sum_{s} h[s]*dinv[s] + h[d]*dinv[d]) + b
// 256 threads = 8 groups of 32 lanes; one node per group; float4 row segments;
// edge loop unrolled x4 for memory-level parallelism.

__global__ __launch_bounds__(256) void k_agg128(const float* __restrict__ h,
                                                const float* __restrict__ dinv,
                                                const int* __restrict__ rowptr,
                                                const int* __restrict__ csr,
                                                const float* __restrict__ bias,
                                                float* __restrict__ out,
                                                int relu, int N) {
    int t = threadIdx.x;
    int g = t >> 5;
    int l = t & 31;
    int node = blockIdx.x * 8 + g;
    if (node >= N) return;
    const float4* h4 = (const float4*)h;
    float dn = dinv[node];
    float4 acc = h4[(size_t)node * 32 + l];
    acc.x *= dn; acc.y *= dn; acc.z *= dn; acc.w *= dn;
    int e0 = rowptr[node], e1 = rowptr[node + 1];
    int e = e0;
    for (; e + 4 <= e1; e += 4) {
        int s0 = csr[e], s1 = csr[e + 1], s2 = csr[e + 2], s3 = csr[e + 3];
        float w0 = dinv[s0], w1 = dinv[s1], w2 = dinv[s2], w3 = dinv[s3];
        float4 v0 = h4[(size_t)s0 * 32 + l];
        float4 v1 = h4[(size_t)s1 * 32 + l];
        float4 v2 = h4[(size_t)s2 * 32 + l];
        float4 v3 = h4[(size_t)s3 * 32 + l];
        acc.x += v0.x * w0 + v1.x * w1 + v2.x * w2 + v3.x * w3;
        acc.y += v0.y * w0 + v1.y * w1 + v2.y * w2 + v3.y * w3;
        acc.z += v0.z * w0 + v1.z * w1 + v2.z * w2 + v3.z * w3;
        acc.w += v0.w * w0 + v1.w * w1 + v2.w * w2 + v3.w * w3;
    }
    for (; e < e1; e++) {
        int s = csr[e];
        float w = dinv[s];
        float4 v = h4[(size_t)s * 32 + l];
        acc.x += v.x * w; acc.y += v.y * w; acc.z += v.z * w; acc.w += v.w * w;
    }
    float4 bb = ((const float4*)bias)[l];
    float4 o;
    o.x = acc.x * dn + bb.x;
    o.y = acc.y * dn + bb.y;
    o.z = acc.z * dn + bb.z;
    o.w = acc.w * dn + bb.w;
    if (relu) {
        o.x = fmaxf(o.x, 0.f); o.y = fmaxf(o.y, 0.f);
        o.z = fmaxf(o.z, 0.f); o.w = fmaxf(o.w, 0.f);
    }
    ((float4*)out)[(size_t)node * 32 + l] = o;
}

// 256 threads: 6 nodes x 40 lanes (threads 240..255 idle); edge loop unrolled x4
__global__ __launch_bounds__(256) void k_agg40(const float* __restrict__ h,
                                               const float* __restrict__ dinv,
                                               const int* __restrict__ rowptr,
                                               const int* __restrict__ csr,
                                               const float* __restrict__ bias,
                                               float* __restrict__ out, int N) {
    int t = threadIdx.x;
    if (t >= 240) return;
    int g = t / 40;
    int l = t - g * 40;
    int node = blockIdx.x * 6 + g;
    if (node >= N) return;
    float dn = dinv[node];
    float acc = h[(size_t)node * 40 + l] * dn;
    int e0 = rowptr[node], e1 = rowptr[node + 1];
    int e = e0;
    for (; e + 4 <= e1; e += 4) {
        int s0 = csr[e], s1 = csr[e + 1], s2 = csr[e + 2], s3 = csr[e + 3];
        float w0 = dinv[s0], w1 = dinv[s1], w2 = dinv[s2], w3 = dinv[s3];
        float v0 = h[(size_t)s0 * 40 + l];
        float v1 = h[(size_t)s1 * 40 + l];
        float v2 = h[(size_t)s2 * 40 + l];
        float v3 = h[(size_t)s3 * 40 + l];
        acc += v0 * w0 + v1 * w1 + v2 * w2 + v3 * w3;
    }
    for (; e < e1; e++) {
        int s = csr[e];
        acc += h[(size_t)s * 40 + l] * dinv[s];
    }
    out[(size_t)node * 40 + l] = acc * dn + bias[l];
}

// ---------------- launch ----------------

extern "C" void kernel_launch(void* const* d_in, const int* in_sizes, int n_in,
                              void* d_out, int out_size, void* d_ws, size_t ws_size,
                              hipStream_t stream) {
    const float* x  = (const float*)d_in[0];
    const int* eidx = (const int*)d_in[1];
    const float* W1 = (const float*)d_in[2];
    const float* b1 = (const float*)d_in[3];
    const float* Wm = (const float*)d_in[4];
    const float* bm = (const float*)d_in[5];
    const float* W2 = (const float*)d_in[6];
    const float* b2 = (const float*)d_in[7];
    float* out = (float*)d_out;

    int N = in_sizes[0] / 128;
    int E = in_sizes[1] / 2;
    const int* src = eidx;
    const int* dst = eidx + E;

    char* ws = (char*)d_ws;
    size_t off = 0;
    auto alloc = [&](size_t bytes) -> void* {
        void* p = ws + off;
        off += (bytes + 255) & ~(size_t)255;
        return p;
    };
    int*   deg    = (int*)alloc((size_t)N * 4);
    float* dinv   = (float*)alloc((size_t)N * 4);
    int*   rowptr = (int*)alloc(((size_t)N + 1) * 4);
    int*   cursor = (int*)alloc(((size_t)N + 1) * 4);
    int*   csr    = (int*)alloc((size_t)E * 4);
    int*   bsum   = (int*)alloc(256 * 4);
    float* bufA   = (float*)alloc((size_t)N * 128 * 4);
    float* bufB   = (float*)alloc((size_t)N * 128 * 4);

    hipMemsetAsync(deg, 0, (size_t)N * 4, stream);
    k_deg<<<(E + 255) / 256, 256, 0, stream>>>(dst, deg, E);
    k_dinv<<<(N + 255) / 256, 256, 0, stream>>>(deg, dinv, N);
    k_scan_p1<<<256, 256, 0, stream>>>(deg, bsum, N);
    k_scan_p2<<<1, 256, 0, stream>>>(bsum);
    k_scan_p3<<<256, 256, 0, stream>>>(deg, bsum, rowptr, cursor, N);
    k_fill<<<(E + 255) / 256, 256, 0, stream>>>(src, dst, cursor, csr, E);

    // layer 1: h1 = relu(agg(x @ W1) + b1)
    k_gemm128<<<(N + 127) / 128, 256, 0, stream>>>(x, W1, bufA, N);
    k_agg128<<<(N + 7) / 8, 256, 0, stream>>>(bufA, dinv, rowptr, csr, b1, bufB, 1, N);
    // layer 2: h2 = relu(agg(h1 @ Wm) + bm)
    k_gemm128<<<(N + 127) / 128, 256, 0, stream>>>(bufB, Wm, bufA, N);
    k_agg128<<<(N + 7) / 8, 256, 0, stream>>>(bufA, dinv, rowptr, csr, bm, bufB, 1, N);
    // layer 3: out = agg(h2 @ W2) + b2
    k_gemm40<<<(N + 63) / 64, 256, 0, stream>>>(bufB, W2, bufA, N);
    k_agg40<<<(N + 5) / 6, 256, 0, stream>>>(bufA, dinv, rowptr, csr, b2, out, N);
}

// Round 4
// 593.687 us; speedup vs baseline: 1.9127x; 1.3169x over previous
//
#include <hip/hip_runtime.h>
#include <hip/hip_bf16.h>

typedef __attribute__((ext_vector_type(8))) short bf16x8;
typedef __attribute__((ext_vector_type(4))) float f32x4;

__device__ __forceinline__ ushort bf16rne(float f) {
    uint u = __float_as_uint(f);
    return (ushort)((u + 0x7fffu + ((u >> 16) & 1u)) >> 16);
}
__device__ __forceinline__ void unpack2(uint p, float& a, float& b) {
    a = __uint_as_float(p << 16);
    b = __uint_as_float(p & 0xffff0000u);
}

// ---------------- graph preprocessing ----------------

__global__ void k_deg(const int* __restrict__ dst, int* __restrict__ deg, int E) {
    int i = blockIdx.x * blockDim.x + threadIdx.x;
    if (i < E) atomicAdd(&deg[dst[i]], 1);
}

__global__ void k_dinv(const int* __restrict__ deg, float* __restrict__ dinv, int N) {
    int i = blockIdx.x * blockDim.x + threadIdx.x;
    if (i < N) dinv[i] = rsqrtf((float)(deg[i] + 1));  // +1 = self-loop
}

__global__ void k_scan_p1(const int* __restrict__ deg, int* __restrict__ bsum, int N) {
    __shared__ int red[256];
    int chunk = (N + 255) / 256;
    int lo = blockIdx.x * chunk;
    int hi = min(lo + chunk, N);
    int s = 0;
    for (int i = lo + (int)threadIdx.x; i < hi; i += 256) s += deg[i];
    red[threadIdx.x] = s;
    __syncthreads();
    for (int d = 128; d > 0; d >>= 1) {
        if ((int)threadIdx.x < d) red[threadIdx.x] += red[threadIdx.x + d];
        __syncthreads();
    }
    if (threadIdx.x == 0) bsum[blockIdx.x] = red[0];
}

__global__ void k_scan_p2(int* __restrict__ bsum) {
    __shared__ int s[256];
    int t = threadIdx.x;
    s[t] = bsum[t];
    __syncthreads();
    for (int d = 1; d < 256; d <<= 1) {
        int u = (t >= d) ? s[t - d] : 0;
        __syncthreads();
        if (t >= d) s[t] += u;
        __syncthreads();
    }
    bsum[t] = (t == 0) ? 0 : s[t - 1];
}

__global__ void k_scan_p3(const int* __restrict__ deg, const int* __restrict__ bsum,
                          int* __restrict__ rowptr, int* __restrict__ cursor, int N) {
    __shared__ int s[256];
    __shared__ int carry;
    int chunk = (N + 255) / 256;
    int lo = blockIdx.x * chunk;
    int hi = min(lo + chunk, N);
    int t = threadIdx.x;
    if (t == 0) carry = bsum[blockIdx.x];
    __syncthreads();
    for (int base = lo; base < hi; base += 256) {
        int i = base + t;
        int v = (i < hi) ? deg[i] : 0;
        s[t] = v;
        __syncthreads();
        for (int d = 1; d < 256; d <<= 1) {
            int u = (t >= d) ? s[t - d] : 0;
            __syncthreads();
            if (t >= d) s[t] += u;
            __syncthreads();
        }
        int excl = carry + ((t == 0) ? 0 : s[t - 1]);
        if (i < hi) { rowptr[i] = excl; cursor[i] = excl; }
        __syncthreads();
        if (t == 0) carry += s[255];
        __syncthreads();
    }
    if (blockIdx.x == gridDim.x - 1 && t == 0) rowptr[N] = carry;
}

__global__ void k_fill(const int* __restrict__ src, const int* __restrict__ dst,
                       int* __restrict__ cursor, int* __restrict__ csr, int E) {
    int i = blockIdx.x * blockDim.x + threadIdx.x;
    if (i < E) {
        int d = dst[i];
        int pos = atomicAdd(&cursor[d], 1);
        csr[pos] = src[i];
    }
}

// ---------------- casts ----------------

__global__ void k_cast_bf16(const float* __restrict__ in, ushort* __restrict__ outp, int n4) {
    int i = blockIdx.x * blockDim.x + threadIdx.x;
    if (i < n4) {
        float4 v = ((const float4*)in)[i];
        uint p0 = (uint)bf16rne(v.x) | ((uint)bf16rne(v.y) << 16);
        uint p1 = (uint)bf16rne(v.z) | ((uint)bf16rne(v.w) << 16);
        ((uint2*)outp)[i] = make_uint2(p0, p1);
    }
}

// W[128x128] fp32 -> Wt[n][k] bf16 (transposed)
__global__ void k_castT(const float* __restrict__ W, ushort* __restrict__ Wt) {
    int i = blockIdx.x * 256 + threadIdx.x;  // 16384 total
    int k = i >> 7, n = i & 127;
    Wt[n * 128 + k] = bf16rne(W[k * 128 + n]);
}

// ---------------- MFMA GEMM: C[M x 128](bf16) = A[M x 128](bf16) @ W, Wt[n][k] bf16 ----------------
// 256 threads = 4 waves; wave computes 16 rows x 128 cols; block = 64 rows.

__global__ __launch_bounds__(256) void k_gemm128_mfma(const ushort* __restrict__ A,
                                                      const ushort* __restrict__ Wt,
                                                      ushort* __restrict__ C, int M) {
    int t = threadIdx.x;
    int wave = t >> 6;
    int lane = t & 63;
    int m16 = lane & 15;
    int quad = lane >> 4;
    int rowA = blockIdx.x * 64 + wave * 16 + m16;
    int rA = min(rowA, M - 1);

    f32x4 acc[8];
#pragma unroll
    for (int i = 0; i < 8; i++) acc[i] = (f32x4){0.f, 0.f, 0.f, 0.f};

#pragma unroll
    for (int k0 = 0; k0 < 128; k0 += 32) {
        bf16x8 a = *(const bf16x8*)(A + (size_t)rA * 128 + k0 + quad * 8);
#pragma unroll
        for (int nt = 0; nt < 8; nt++) {
            bf16x8 b = *(const bf16x8*)(Wt + (size_t)(nt * 16 + m16) * 128 + k0 + quad * 8);
            acc[nt] = __builtin_amdgcn_mfma_f32_16x16x32_bf16(a, b, acc[nt], 0, 0, 0);
        }
    }
    int rowBase = blockIdx.x * 64 + wave * 16 + quad * 4;
#pragma unroll
    for (int nt = 0; nt < 8; nt++) {
        int col = nt * 16 + m16;
#pragma unroll
        for (int r = 0; r < 4; r++) {
            int row = rowBase + r;
            if (row < M) C[(size_t)row * 128 + col] = bf16rne(acc[nt][r]);
        }
    }
}

// ---------------- GEMM: C[M x 40](bf16) = A[M x 128](bf16) @ W2[128 x 40](fp32) ----------------

__global__ __launch_bounds__(256) void k_gemm40_b(const ushort* __restrict__ A,
                                                  const float* __restrict__ W,
                                                  ushort* __restrict__ C, int M) {
    __shared__ float As[64][132];
    __shared__ float Ws[128][40];
    int t = threadIdx.x;
    int r = t >> 2;
    int c0 = t & 3;
    int row0 = blockIdx.x * 64;

    float* wflat = &Ws[0][0];
#pragma unroll
    for (int f = t; f < 1280; f += 256)
        *(float4*)&wflat[f * 4] = *(const float4*)(W + (size_t)f * 4);
    // A tile: 64 rows x 128 bf16 = 64 x 64 uints
#pragma unroll
    for (int f = t; f < 4096; f += 256) {
        int rr = f >> 6, q = f & 63;
        int row = row0 + rr;
        uint p = 0;
        if (row < M) p = ((const uint*)A)[(size_t)row * 64 + q];
        float a0, a1;
        unpack2(p, a0, a1);
        As[rr][q * 2] = a0;
        As[rr][q * 2 + 1] = a1;
    }
    __syncthreads();

    float acc[10];
#pragma unroll
    for (int j = 0; j < 10; j++) acc[j] = 0.f;
    for (int k = 0; k < 128; k++) {
        float a = As[r][k];
#pragma unroll
        for (int j = 0; j < 10; j++) acc[j] += a * Ws[k][c0 + 4 * j];
    }
    int row = row0 + r;
    if (row < M) {
#pragma unroll
        for (int j = 0; j < 10; j++) C[(size_t)row * 40 + c0 + 4 * j] = bf16rne(acc[j]);
    }
}

// ---------------- aggregation (bf16 features, fp32 accumulate) ----------------
// out[d] = dinv[d]*(sum_s g[s]*dinv[s] + g[d]*dinv[d]) + b
// 8 groups x 32 lanes; lane covers 4 bf16 (8 B); edge loop unrolled x4.

__global__ __launch_bounds__(256) void k_agg128_b(const ushort* __restrict__ g,
                                                  const float* __restrict__ dinv,
                                                  const int* __restrict__ rowptr,
                                                  const int* __restrict__ csr,
                                                  const float* __restrict__ bias,
                                                  ushort* __restrict__ hout,
                                                  int relu, int N) {
    int t = threadIdx.x;
    int grp = t >> 5;
    int l = t & 31;
    int node = blockIdx.x * 8 + grp;
    if (node >= N) return;
    const uint2* g8 = (const uint2*)g;  // 32 uint2 per 128-bf16 row
    float dn = dinv[node];
    float4 acc;
    {
        uint2 p = g8[(size_t)node * 32 + l];
        float f0, f1, f2, f3;
        unpack2(p.x, f0, f1);
        unpack2(p.y, f2, f3);
        acc.x = f0 * dn; acc.y = f1 * dn; acc.z = f2 * dn; acc.w = f3 * dn;
    }
    int e0 = rowptr[node], e1 = rowptr[node + 1];
    int e = e0;
    for (; e + 4 <= e1; e += 4) {
        int s0 = csr[e], s1 = csr[e + 1], s2 = csr[e + 2], s3 = csr[e + 3];
        float w0 = dinv[s0], w1 = dinv[s1], w2 = dinv[s2], w3 = dinv[s3];
        uint2 p0 = g8[(size_t)s0 * 32 + l];
        uint2 p1 = g8[(size_t)s1 * 32 + l];
        uint2 p2 = g8[(size_t)s2 * 32 + l];
        uint2 p3 = g8[(size_t)s3 * 32 + l];
        float a0, a1, a2, a3;
        unpack2(p0.x, a0, a1); unpack2(p0.y, a2, a3);
        acc.x += a0 * w0; acc.y += a1 * w0; acc.z += a2 * w0; acc.w += a3 * w0;
        unpack2(p1.x, a0, a1); unpack2(p1.y, a2, a3);
        acc.x += a0 * w1; acc.y += a1 * w1; acc.z += a2 * w1; acc.w += a3 * w1;
        unpack2(p2.x, a0, a1); unpack2(p2.y, a2, a3);
        acc.x += a0 * w2; acc.y += a1 * w2; acc.z += a2 * w2; acc.w += a3 * w2;
        unpack2(p3.x, a0, a1); unpack2(p3.y, a2, a3);
        acc.x += a0 * w3; acc.y += a1 * w3; acc.z += a2 * w3; acc.w += a3 * w3;
    }
    for (; e < e1; e++) {
        int s = csr[e];
        float w = dinv[s];
        uint2 p = g8[(size_t)s * 32 + l];
        float a0, a1, a2, a3;
        unpack2(p.x, a0, a1); unpack2(p.y, a2, a3);
        acc.x += a0 * w; acc.y += a1 * w; acc.z += a2 * w; acc.w += a3 * w;
    }
    float4 bb = ((const float4*)bias)[l];
    float4 o;
    o.x = acc.x * dn + bb.x;
    o.y = acc.y * dn + bb.y;
    o.z = acc.z * dn + bb.z;
    o.w = acc.w * dn + bb.w;
    if (relu) {
        o.x = fmaxf(o.x, 0.f); o.y = fmaxf(o.y, 0.f);
        o.z = fmaxf(o.z, 0.f); o.w = fmaxf(o.w, 0.f);
    }
    uint q0 = (uint)bf16rne(o.x) | ((uint)bf16rne(o.y) << 16);
    uint q1 = (uint)bf16rne(o.z) | ((uint)bf16rne(o.w) << 16);
    ((uint2*)hout)[(size_t)node * 32 + l] = make_uint2(q0, q1);
}

// g3 rows = 40 bf16 = 20 uints; 12 groups x 20 lanes; fp32 output.
__global__ __launch_bounds__(256) void k_agg40_b(const ushort* __restrict__ g3,
                                                 const float* __restrict__ dinv,
                                                 const int* __restrict__ rowptr,
                                                 const int* __restrict__ csr,
                                                 const float* __restrict__ bias,
                                                 float* __restrict__ out, int N) {
    int t = threadIdx.x;
    if (t >= 240) return;
    int grp = t / 20;
    int l = t - grp * 20;
    int node = blockIdx.x * 12 + grp;
    if (node >= N) return;
    const uint* gp = (const uint*)g3;
    float dn = dinv[node];
    float a0, a1;
    {
        uint p = gp[(size_t)node * 20 + l];
        unpack2(p, a0, a1);
        a0 *= dn; a1 *= dn;
    }
    int e0 = rowptr[node], e1 = rowptr[node + 1];
    int e = e0;
    for (; e + 4 <= e1; e += 4) {
        int s0 = csr[e], s1 = csr[e + 1], s2 = csr[e + 2], s3 = csr[e + 3];
        float w0 = dinv[s0], w1 = dinv[s1], w2 = dinv[s2], w3 = dinv[s3];
        uint p0 = gp[(size_t)s0 * 20 + l];
        uint p1 = gp[(size_t)s1 * 20 + l];
        uint p2 = gp[(size_t)s2 * 20 + l];
        uint p3 = gp[(size_t)s3 * 20 + l];
        float u, v;
        unpack2(p0, u, v); a0 += u * w0; a1 += v * w0;
        unpack2(p1, u, v); a0 += u * w1; a1 += v * w1;
        unpack2(p2, u, v); a0 += u * w2; a1 += v * w2;
        unpack2(p3, u, v); a0 += u * w3; a1 += v * w3;
    }
    for (; e < e1; e++) {
        int s = csr[e];
        float w = dinv[s];
        float u, v;
        unpack2(gp[(size_t)s * 20 + l], u, v);
        a0 += u * w; a1 += v * w;
    }
    float2 o;
    o.x = a0 * dn + bias[2 * l];
    o.y = a1 * dn + bias[2 * l + 1];
    ((float2*)out)[(size_t)node * 20 + l] = o;
}

// ---------------- launch ----------------

extern "C" void kernel_launch(void* const* d_in, const int* in_sizes, int n_in,
                              void* d_out, int out_size, void* d_ws, size_t ws_size,
                              hipStream_t stream) {
    const float* x  = (const float*)d_in[0];
    const int* eidx = (const int*)d_in[1];
    const float* W1 = (const float*)d_in[2];
    const float* b1 = (const float*)d_in[3];
    const float* Wm = (const float*)d_in[4];
    const float* bm = (const float*)d_in[5];
    const float* W2 = (const float*)d_in[6];
    const float* b2 = (const float*)d_in[7];
    float* out = (float*)d_out;

    int N = in_sizes[0] / 128;
    int E = in_sizes[1] / 2;
    const int* src = eidx;
    const int* dst = eidx + E;

    char* ws = (char*)d_ws;
    size_t off = 0;
    auto alloc = [&](size_t bytes) -> void* {
        void* p = ws + off;
        off += (bytes + 255) & ~(size_t)255;
        return p;
    };
    int*    deg    = (int*)alloc((size_t)N * 4);
    float*  dinv   = (float*)alloc((size_t)N * 4);
    int*    rowptr = (int*)alloc(((size_t)N + 1) * 4);
    int*    cursor = (int*)alloc(((size_t)N + 1) * 4);
    int*    csr    = (int*)alloc((size_t)E * 4);
    int*    bsum   = (int*)alloc(256 * 4);
    ushort* xb     = (ushort*)alloc((size_t)N * 128 * 2);
    ushort* w1t    = (ushort*)alloc(128 * 128 * 2);
    ushort* wmt    = (ushort*)alloc(128 * 128 * 2);
    ushort* gbuf   = (ushort*)alloc((size_t)N * 128 * 2);
    ushort* hbuf   = (ushort*)alloc((size_t)N * 128 * 2);

    hipMemsetAsync(deg, 0, (size_t)N * 4, stream);
    k_deg<<<(E + 255) / 256, 256, 0, stream>>>(dst, deg, E);
    k_dinv<<<(N + 255) / 256, 256, 0, stream>>>(deg, dinv, N);
    k_scan_p1<<<256, 256, 0, stream>>>(deg, bsum, N);
    k_scan_p2<<<1, 256, 0, stream>>>(bsum);
    k_scan_p3<<<256, 256, 0, stream>>>(deg, bsum, rowptr, cursor, N);
    k_fill<<<(E + 255) / 256, 256, 0, stream>>>(src, dst, cursor, csr, E);

    // casts
    int n4 = N * 128 / 4;
    k_cast_bf16<<<(n4 + 255) / 256, 256, 0, stream>>>(x, xb, n4);
    k_castT<<<64, 256, 0, stream>>>(W1, w1t);
    k_castT<<<64, 256, 0, stream>>>(Wm, wmt);

    int gblk = (N + 63) / 64;
    // layer 1
    k_gemm128_mfma<<<gblk, 256, 0, stream>>>(xb, w1t, gbuf, N);
    k_agg128_b<<<(N + 7) / 8, 256, 0, stream>>>(gbuf, dinv, rowptr, csr, b1, hbuf, 1, N);
    // layer 2
    k_gemm128_mfma<<<gblk, 256, 0, stream>>>(hbuf, wmt, gbuf, N);
    k_agg128_b<<<(N + 7) / 8, 256, 0, stream>>>(gbuf, dinv, rowptr, csr, bm, hbuf, 1, N);
    // layer 3: g3 (bf16, stored in gbuf) then fp32 out
    k_gemm40_b<<<(N + 63) / 64, 256, 0, stream>>>(hbuf, W2, gbuf, N);
    k_agg40_b<<<(N + 11) / 12, 256, 0, stream>>>(gbuf, dinv, rowptr, csr, b2, out, N);
}

// Round 5
// 534.638 us; speedup vs baseline: 2.1240x; 1.1104x over previous
//
#include <hip/hip_runtime.h>
#include <hip/hip_bf16.h>

typedef __attribute__((ext_vector_type(8))) short bf16x8;
typedef __attribute__((ext_vector_type(4))) float f32x4;

__device__ __forceinline__ ushort bf16rne(float f) {
    uint u = __float_as_uint(f);
    return (ushort)((u + 0x7fffu + ((u >> 16) & 1u)) >> 16);
}
__device__ __forceinline__ void unpack2(uint p, float& a, float& b) {
    a = __uint_as_float(p << 16);
    b = __uint_as_float(p & 0xffff0000u);
}

// ---------------- graph preprocessing ----------------

__global__ void k_deg(const int* __restrict__ dst, int* __restrict__ deg, int E) {
    int i = blockIdx.x * blockDim.x + threadIdx.x;
    if (i < E) atomicAdd(&deg[dst[i]], 1);
}

__global__ void k_dinv(const int* __restrict__ deg, float* __restrict__ dinv, int N) {
    int i = blockIdx.x * blockDim.x + threadIdx.x;
    if (i < N) dinv[i] = rsqrtf((float)(deg[i] + 1));  // +1 = self-loop
}

__global__ void k_scan_p1(const int* __restrict__ deg, int* __restrict__ bsum, int N) {
    __shared__ int red[256];
    int chunk = (N + 255) / 256;
    int lo = blockIdx.x * chunk;
    int hi = min(lo + chunk, N);
    int s = 0;
    for (int i = lo + (int)threadIdx.x; i < hi; i += 256) s += deg[i];
    red[threadIdx.x] = s;
    __syncthreads();
    for (int d = 128; d > 0; d >>= 1) {
        if ((int)threadIdx.x < d) red[threadIdx.x] += red[threadIdx.x + d];
        __syncthreads();
    }
    if (threadIdx.x == 0) bsum[blockIdx.x] = red[0];
}

__global__ void k_scan_p2(int* __restrict__ bsum) {
    __shared__ int s[256];
    int t = threadIdx.x;
    s[t] = bsum[t];
    __syncthreads();
    for (int d = 1; d < 256; d <<= 1) {
        int u = (t >= d) ? s[t - d] : 0;
        __syncthreads();
        if (t >= d) s[t] += u;
        __syncthreads();
    }
    bsum[t] = (t == 0) ? 0 : s[t - 1];
}

__global__ void k_scan_p3(const int* __restrict__ deg, const int* __restrict__ bsum,
                          int* __restrict__ rowptr, int* __restrict__ cursor, int N) {
    __shared__ int s[256];
    __shared__ int carry;
    int chunk = (N + 255) / 256;
    int lo = blockIdx.x * chunk;
    int hi = min(lo + chunk, N);
    int t = threadIdx.x;
    if (t == 0) carry = bsum[blockIdx.x];
    __syncthreads();
    for (int base = lo; base < hi; base += 256) {
        int i = base + t;
        int v = (i < hi) ? deg[i] : 0;
        s[t] = v;
        __syncthreads();
        for (int d = 1; d < 256; d <<= 1) {
            int u = (t >= d) ? s[t - d] : 0;
            __syncthreads();
            if (t >= d) s[t] += u;
            __syncthreads();
        }
        int excl = carry + ((t == 0) ? 0 : s[t - 1]);
        if (i < hi) { rowptr[i] = excl; cursor[i] = excl; }
        __syncthreads();
        if (t == 0) carry += s[255];
        __syncthreads();
    }
    if (blockIdx.x == gridDim.x - 1 && t == 0) rowptr[N] = carry;
}

// ---------------- bucketed CSR build (replaces global-scatter k_fill) ----------------
// buckets of 256 nodes: bucket = dst >> 8. Packed entry: (dst&255)<<24 | src.
// Assumes N <= 131072 (nbuck <= 512) and src < 2^24.

__global__ void k_binit(const int* __restrict__ rowptr, int* __restrict__ bcur,
                        int N, int nbuck) {
    int b = blockIdx.x * 256 + threadIdx.x;
    if (b < nbuck) bcur[b] = rowptr[min(b << 8, N)];
}

__global__ __launch_bounds__(256) void k_binpack(const int* __restrict__ src,
                                                 const int* __restrict__ dst,
                                                 int* __restrict__ bcur,
                                                 uint* __restrict__ pairbuf,
                                                 int E, int nbuck) {
    __shared__ int hist[512];
    __shared__ int scn[512];     // inclusive scan of hist
    __shared__ int cur[512];     // scatter cursors (exclusive scan, bumped)
    __shared__ int gbase[512];   // reserved global base per bucket
    __shared__ uint sorted[4096];
    int t = threadIdx.x;
    int off = blockIdx.x * 4096;
    int cnt = min(4096, E - off);

    hist[t] = 0; hist[t + 256] = 0;
    __syncthreads();
    for (int i = t; i < cnt; i += 256) {
        int b = dst[off + i] >> 8;
        atomicAdd(&hist[b], 1);
    }
    __syncthreads();
    // two half-scans (Hillis-Steele inclusive), then offset second half
    scn[t] = hist[t]; scn[t + 256] = hist[t + 256];
    __syncthreads();
    for (int d = 1; d < 256; d <<= 1) {
        int u0 = (t >= d) ? scn[t - d] : 0;
        int u1 = (t >= d) ? scn[256 + t - d] : 0;
        __syncthreads();
        if (t >= d) { scn[t] += u0; scn[256 + t] += u1; }
        __syncthreads();
    }
    int tot0 = scn[255];
    scn[256 + t] += tot0;   // each thread updates a unique second-half slot
    __syncthreads();
    // exclusive scan into cur; reserve global runs
    cur[t] = (t == 0) ? 0 : scn[t - 1];
    cur[t + 256] = scn[t + 255];
    if (t < nbuck && hist[t] > 0) gbase[t] = atomicAdd(&bcur[t], hist[t]);
    int t2 = t + 256;
    if (t2 < nbuck && hist[t2] > 0) gbase[t2] = atomicAdd(&bcur[t2], hist[t2]);
    __syncthreads();
    // scatter into LDS, bucket-sorted
    for (int i = t; i < cnt; i += 256) {
        int d = dst[off + i];
        int s = src[off + i];
        int b = d >> 8;
        int pos = atomicAdd(&cur[b], 1);
        sorted[pos] = ((uint)(d & 255) << 24) | (uint)s;
    }
    __syncthreads();
    // flush: one wave per bucket round-robin, contiguous run writes
    int wid = t >> 6, lane = t & 63;
    for (int b = wid; b < nbuck; b += 4) {
        int n = hist[b];
        if (n == 0) continue;
        int ls = (b == 0) ? 0 : scn[b - 1];
        int gb = gbase[b];
        for (int j = lane; j < n; j += 64)
            pairbuf[gb + j] = sorted[ls + j];
    }
}

#define CSR_CAP 5632
__global__ __launch_bounds__(256) void k_csrbuild(const uint* __restrict__ pairbuf,
                                                  const int* __restrict__ rowptr,
                                                  int* __restrict__ cursor,
                                                  int* __restrict__ csr, int N) {
    __shared__ int lcur[256];
    __shared__ int lcsr[CSR_CAP];
    int b = blockIdx.x;
    int base = b << 8;
    int nn = min(256, N - base);
    int lo = rowptr[base];
    int hi = rowptr[base + nn];
    int cnt = hi - lo;
    int t = threadIdx.x;
    if (cnt <= CSR_CAP) {
        if (t < nn) lcur[t] = rowptr[base + t] - lo;
        __syncthreads();
        for (int i = t; i < cnt; i += 256) {
            uint p = pairbuf[lo + i];
            int dl = p >> 24;
            int pos = atomicAdd(&lcur[dl], 1);
            lcsr[pos] = (int)(p & 0xFFFFFFu);
        }
        __syncthreads();
        for (int i = t; i < cnt; i += 256) csr[lo + i] = lcsr[i];
    } else {
        // statistical overflow fallback: global scatter via per-node cursor
        for (int i = t; i < cnt; i += 256) {
            uint p = pairbuf[lo + i];
            int dl = p >> 24;
            int pos = atomicAdd(&cursor[base + dl], 1);
            csr[pos] = (int)(p & 0xFFFFFFu);
        }
    }
}

// ---------------- casts ----------------

__global__ void k_cast_bf16(const float* __restrict__ in, ushort* __restrict__ outp, int n4) {
    int i = blockIdx.x * blockDim.x + threadIdx.x;
    if (i < n4) {
        float4 v = ((const float4*)in)[i];
        uint p0 = (uint)bf16rne(v.x) | ((uint)bf16rne(v.y) << 16);
        uint p1 = (uint)bf16rne(v.z) | ((uint)bf16rne(v.w) << 16);
        ((uint2*)outp)[i] = make_uint2(p0, p1);
    }
}

// W[128x128] fp32 -> Wt[n][k] bf16 (transposed)
__global__ void k_castT(const float* __restrict__ W, ushort* __restrict__ Wt) {
    int i = blockIdx.x * 256 + threadIdx.x;  // 16384 total
    int k = i >> 7, n = i & 127;
    Wt[n * 128 + k] = bf16rne(W[k * 128 + n]);
}

// ---------------- MFMA GEMM: C[M x 128](bf16) = (A[M x 128](bf16) @ W) * dinv[row] ----------------
// 256 threads = 4 waves; wave computes 16 rows x 128 cols; block = 64 rows.
// Output pre-scaled by dinv[row] so agg needs no per-edge dinv gather.

__global__ __launch_bounds__(256) void k_gemm128_mfma(const ushort* __restrict__ A,
                                                      const ushort* __restrict__ Wt,
                                                      const float* __restrict__ dinv,
                                                      ushort* __restrict__ C, int M) {
    int t = threadIdx.x;
    int wave = t >> 6;
    int lane = t & 63;
    int m16 = lane & 15;
    int quad = lane >> 4;
    int rowA = blockIdx.x * 64 + wave * 16 + m16;
    int rA = min(rowA, M - 1);

    f32x4 acc[8];
#pragma unroll
    for (int i = 0; i < 8; i++) acc[i] = (f32x4){0.f, 0.f, 0.f, 0.f};

#pragma unroll
    for (int k0 = 0; k0 < 128; k0 += 32) {
        bf16x8 a = *(const bf16x8*)(A + (size_t)rA * 128 + k0 + quad * 8);
#pragma unroll
        for (int nt = 0; nt < 8; nt++) {
            bf16x8 b = *(const bf16x8*)(Wt + (size_t)(nt * 16 + m16) * 128 + k0 + quad * 8);
            acc[nt] = __builtin_amdgcn_mfma_f32_16x16x32_bf16(a, b, acc[nt], 0, 0, 0);
        }
    }
    int rowBase = blockIdx.x * 64 + wave * 16 + quad * 4;
    float dnv[4];
#pragma unroll
    for (int r = 0; r < 4; r++) dnv[r] = dinv[min(rowBase + r, M - 1)];
#pragma unroll
    for (int nt = 0; nt < 8; nt++) {
        int col = nt * 16 + m16;
#pragma unroll
        for (int r = 0; r < 4; r++) {
            int row = rowBase + r;
            if (row < M) C[(size_t)row * 128 + col] = bf16rne(acc[nt][r] * dnv[r]);
        }
    }
}

// ---------------- GEMM: C[M x 40](bf16) = (A[M x 128](bf16) @ W2[128 x 40](fp32)) * dinv[row] ----------------

__global__ __launch_bounds__(256) void k_gemm40_b(const ushort* __restrict__ A,
                                                  const float* __restrict__ W,
                                                  const float* __restrict__ dinv,
                                                  ushort* __restrict__ C, int M) {
    __shared__ float As[64][132];
    __shared__ float Ws[128][40];
    int t = threadIdx.x;
    int r = t >> 2;
    int c0 = t & 3;
    int row0 = blockIdx.x * 64;

    float* wflat = &Ws[0][0];
#pragma unroll
    for (int f = t; f < 1280; f += 256)
        *(float4*)&wflat[f * 4] = *(const float4*)(W + (size_t)f * 4);
#pragma unroll
    for (int f = t; f < 4096; f += 256) {
        int rr = f >> 6, q = f & 63;
        int row = row0 + rr;
        uint p = 0;
        if (row < M) p = ((const uint*)A)[(size_t)row * 64 + q];
        float a0, a1;
        unpack2(p, a0, a1);
        As[rr][q * 2] = a0;
        As[rr][q * 2 + 1] = a1;
    }
    __syncthreads();

    float acc[10];
#pragma unroll
    for (int j = 0; j < 10; j++) acc[j] = 0.f;
    for (int k = 0; k < 128; k++) {
        float a = As[r][k];
#pragma unroll
        for (int j = 0; j < 10; j++) acc[j] += a * Ws[k][c0 + 4 * j];
    }
    int row = row0 + r;
    if (row < M) {
        float dn = dinv[row];
#pragma unroll
        for (int j = 0; j < 10; j++) C[(size_t)row * 40 + c0 + 4 * j] = bf16rne(acc[j] * dn);
    }
}

// ---------------- aggregation (bf16 pre-scaled features, fp32 accumulate) ----------------
// p[s] = g[s]*dinv[s] already; out[d] = dinv[d]*(sum_s p[s] + p[d]) + b
// 8 groups x 32 lanes; lane covers 4 bf16 (8 B); edge loop unrolled x4.

__global__ __launch_bounds__(256) void k_agg128_b(const ushort* __restrict__ g,
                                                  const float* __restrict__ dinv,
                                                  const int* __restrict__ rowptr,
                                                  const int* __restrict__ csr,
                                                  const float* __restrict__ bias,
                                                  ushort* __restrict__ hout,
                                                  int relu, int N) {
    int t = threadIdx.x;
    int grp = t >> 5;
    int l = t & 31;
    int node = blockIdx.x * 8 + grp;
    if (node >= N) return;
    const uint2* g8 = (const uint2*)g;  // 32 uint2 per 128-bf16 row
    float dn = dinv[node];
    float4 acc;
    {
        uint2 p = g8[(size_t)node * 32 + l];
        unpack2(p.x, acc.x, acc.y);
        unpack2(p.y, acc.z, acc.w);
    }
    int e0 = rowptr[node], e1 = rowptr[node + 1];
    int e = e0;
    for (; e + 4 <= e1; e += 4) {
        int s0 = csr[e], s1 = csr[e + 1], s2 = csr[e + 2], s3 = csr[e + 3];
        uint2 p0 = g8[(size_t)s0 * 32 + l];
        uint2 p1 = g8[(size_t)s1 * 32 + l];
        uint2 p2 = g8[(size_t)s2 * 32 + l];
        uint2 p3 = g8[(size_t)s3 * 32 + l];
        float a0, a1, a2, a3;
        unpack2(p0.x, a0, a1); unpack2(p0.y, a2, a3);
        acc.x += a0; acc.y += a1; acc.z += a2; acc.w += a3;
        unpack2(p1.x, a0, a1); unpack2(p1.y, a2, a3);
        acc.x += a0; acc.y += a1; acc.z += a2; acc.w += a3;
        unpack2(p2.x, a0, a1); unpack2(p2.y, a2, a3);
        acc.x += a0; acc.y += a1; acc.z += a2; acc.w += a3;
        unpack2(p3.x, a0, a1); unpack2(p3.y, a2, a3);
        acc.x += a0; acc.y += a1; acc.z += a2; acc.w += a3;
    }
    for (; e < e1; e++) {
        int s = csr[e];
        uint2 p = g8[(size_t)s * 32 + l];
        float a0, a1, a2, a3;
        unpack2(p.x, a0, a1); unpack2(p.y, a2, a3);
        acc.x += a0; acc.y += a1; acc.z += a2; acc.w += a3;
    }
    float4 bb = ((const float4*)bias)[l];
    float4 o;
    o.x = acc.x * dn + bb.x;
    o.y = acc.y * dn + bb.y;
    o.z = acc.z * dn + bb.z;
    o.w = acc.w * dn + bb.w;
    if (relu) {
        o.x = fmaxf(o.x, 0.f); o.y = fmaxf(o.y, 0.f);
        o.z = fmaxf(o.z, 0.f); o.w = fmaxf(o.w, 0.f);
    }
    uint q0 = (uint)bf16rne(o.x) | ((uint)bf16rne(o.y) << 16);
    uint q1 = (uint)bf16rne(o.z) | ((uint)bf16rne(o.w) << 16);
    ((uint2*)hout)[(size_t)node * 32 + l] = make_uint2(q0, q1);
}

// g3 rows = 40 bf16 = 20 uints (pre-scaled); 12 groups x 20 lanes; fp32 output.
__global__ __launch_bounds__(256) void k_agg40_b(const ushort* __restrict__ g3,
                                                 const float* __restrict__ dinv,
                                                 const int* __restrict__ rowptr,
                                                 const int* __restrict__ csr,
                                                 const float* __restrict__ bias,
                                                 float* __restrict__ out, int N) {
    int t = threadIdx.x;
    if (t >= 240) return;
    int grp = t / 20;
    int l = t - grp * 20;
    int node = blockIdx.x * 12 + grp;
    if (node >= N) return;
    const uint* gp = (const uint*)g3;
    float dn = dinv[node];
    float a0, a1;
    unpack2(gp[(size_t)node * 20 + l], a0, a1);
    int e0 = rowptr[node], e1 = rowptr[node + 1];
    int e = e0;
    for (; e + 4 <= e1; e += 4) {
        int s0 = csr[e], s1 = csr[e + 1], s2 = csr[e + 2], s3 = csr[e + 3];
        uint p0 = gp[(size_t)s0 * 20 + l];
        uint p1 = gp[(size_t)s1 * 20 + l];
        uint p2 = gp[(size_t)s2 * 20 + l];
        uint p3 = gp[(size_t)s3 * 20 + l];
        float u, v;
        unpack2(p0, u, v); a0 += u; a1 += v;
        unpack2(p1, u, v); a0 += u; a1 += v;
        unpack2(p2, u, v); a0 += u; a1 += v;
        unpack2(p3, u, v); a0 += u; a1 += v;
    }
    for (; e < e1; e++) {
        int s = csr[e];
        float u, v;
        unpack2(gp[(size_t)s * 20 + l], u, v);
        a0 += u; a1 += v;
    }
    float2 o;
    o.x = a0 * dn + bias[2 * l];
    o.y = a1 * dn + bias[2 * l + 1];
    ((float2*)out)[(size_t)node * 20 + l] = o;
}

// ---------------- launch ----------------

extern "C" void kernel_launch(void* const* d_in, const int* in_sizes, int n_in,
                              void* d_out, int out_size, void* d_ws, size_t ws_size,
                              hipStream_t stream) {
    const float* x  = (const float*)d_in[0];
    const int* eidx = (const int*)d_in[1];
    const float* W1 = (const float*)d_in[2];
    const float* b1 = (const float*)d_in[3];
    const float* Wm = (const float*)d_in[4];
    const float* bm = (const float*)d_in[5];
    const float* W2 = (const float*)d_in[6];
    const float* b2 = (const float*)d_in[7];
    float* out = (float*)d_out;

    int N = in_sizes[0] / 128;
    int E = in_sizes[1] / 2;
    const int* src = eidx;
    const int* dst = eidx + E;
    int nbuck = (N + 255) >> 8;

    char* ws = (char*)d_ws;
    size_t off = 0;
    auto alloc = [&](size_t bytes) -> void* {
        void* p = ws + off;
        off += (bytes + 255) & ~(size_t)255;
        return p;
    };
    int*    deg     = (int*)alloc((size_t)N * 4);
    float*  dinv    = (float*)alloc((size_t)N * 4);
    int*    rowptr  = (int*)alloc(((size_t)N + 1) * 4);
    int*    cursor  = (int*)alloc(((size_t)N + 1) * 4);
    int*    csr     = (int*)alloc((size_t)E * 4);
    uint*   pairbuf = (uint*)alloc((size_t)E * 4);
    int*    bcur    = (int*)alloc(512 * 4);
    int*    bsum    = (int*)alloc(256 * 4);
    ushort* xb      = (ushort*)alloc((size_t)N * 128 * 2);
    ushort* w1t     = (ushort*)alloc(128 * 128 * 2);
    ushort* wmt     = (ushort*)alloc(128 * 128 * 2);
    ushort* gbuf    = (ushort*)alloc((size_t)N * 128 * 2);
    ushort* hbuf    = (ushort*)alloc((size_t)N * 128 * 2);

    hipMemsetAsync(deg, 0, (size_t)N * 4, stream);
    k_deg<<<(E + 255) / 256, 256, 0, stream>>>(dst, deg, E);
    k_dinv<<<(N + 255) / 256, 256, 0, stream>>>(deg, dinv, N);
    k_scan_p1<<<256, 256, 0, stream>>>(deg, bsum, N);
    k_scan_p2<<<1, 256, 0, stream>>>(bsum);
    k_scan_p3<<<256, 256, 0, stream>>>(deg, bsum, rowptr, cursor, N);
    // bucketed CSR build
    k_binit<<<(nbuck + 255) / 256, 256, 0, stream>>>(rowptr, bcur, N, nbuck);
    k_binpack<<<(E + 4095) / 4096, 256, 0, stream>>>(src, dst, bcur, pairbuf, E, nbuck);
    k_csrbuild<<<nbuck, 256, 0, stream>>>(pairbuf, rowptr, cursor, csr, N);

    // casts
    int n4 = N * 128 / 4;
    k_cast_bf16<<<(n4 + 255) / 256, 256, 0, stream>>>(x, xb, n4);
    k_castT<<<64, 256, 0, stream>>>(W1, w1t);
    k_castT<<<64, 256, 0, stream>>>(Wm, wmt);

    int gblk = (N + 63) / 64;
    // layer 1
    k_gemm128_mfma<<<gblk, 256, 0, stream>>>(xb, w1t, dinv, gbuf, N);
    k_agg128_b<<<(N + 7) / 8, 256, 0, stream>>>(gbuf, dinv, rowptr, csr, b1, hbuf, 1, N);
    // layer 2
    k_gemm128_mfma<<<gblk, 256, 0, stream>>>(hbuf, wmt, dinv, gbuf, N);
    k_agg128_b<<<(N + 7) / 8, 256, 0, stream>>>(gbuf, dinv, rowptr, csr, bm, hbuf, 1, N);
    // layer 3
    k_gemm40_b<<<(N + 63) / 64, 256, 0, stream>>>(hbuf, W2, dinv, gbuf, N);
    k_agg40_b<<<(N + 11) / 12, 256, 0, stream>>>(gbuf, dinv, rowptr, csr, b2, out, N);
}

// Round 6
// 471.159 us; speedup vs baseline: 2.4102x; 1.1347x over previous
//
#include <hip/hip_runtime.h>
#include <hip/hip_bf16.h>

typedef __attribute__((ext_vector_type(8))) short bf16x8;
typedef __attribute__((ext_vector_type(4))) float f32x4;

__device__ __forceinline__ ushort bf16rne(float f) {
    uint u = __float_as_uint(f);
    return (ushort)((u + 0x7fffu + ((u >> 16) & 1u)) >> 16);
}
__device__ __forceinline__ void unpack2(uint p, float& a, float& b) {
    a = __uint_as_float(p << 16);
    b = __uint_as_float(p & 0xffff0000u);
}

// ---------------- bucketed graph preprocessing ----------------
// bucket = dst >> 8 (256 nodes per bucket), nbuck <= 512. Packed pair:
// (dst&255)<<24 | src  (src < 2^24).
// Degrees/rowptr/dinv are all DERIVED from the bucket sort — no global
// per-node atomics anywhere.

// per-tile LDS histogram of buckets -> global bucket counts
__global__ __launch_bounds__(256) void k_bhist(const int* __restrict__ dst,
                                               int* __restrict__ bcnt, int E) {
    __shared__ int hist[512];
    int t = threadIdx.x;
    hist[t] = 0; hist[t + 256] = 0;
    __syncthreads();
    int off = blockIdx.x * 4096;
    int cnt = min(4096, E - off);
    for (int i = t; i < cnt; i += 256) atomicAdd(&hist[dst[off + i] >> 8], 1);
    __syncthreads();
    if (hist[t]) atomicAdd(&bcnt[t], hist[t]);
    if (hist[t + 256]) atomicAdd(&bcnt[t + 256], hist[t + 256]);
}

// single tiny block: exclusive scan of bucket counts -> bbase[0..nbuck], bcur copy
__global__ void k_bscan(const int* __restrict__ bcnt, int* __restrict__ bbase,
                        int* __restrict__ bcur, int nbuck) {
    __shared__ int s[512];
    int t = threadIdx.x;  // 512
    s[t] = (t < nbuck) ? bcnt[t] : 0;
    __syncthreads();
    for (int d = 1; d < 512; d <<= 1) {
        int u = (t >= d) ? s[t - d] : 0;
        __syncthreads();
        if (t >= d) s[t] += u;
        __syncthreads();
    }
    int excl = (t == 0) ? 0 : s[t - 1];
    bbase[t] = excl;
    if (t < nbuck) bcur[t] = excl;
    if (t == 511) bbase[512] = s[511];
}

__global__ __launch_bounds__(256) void k_binpack(const int* __restrict__ src,
                                                 const int* __restrict__ dst,
                                                 int* __restrict__ bcur,
                                                 uint* __restrict__ pairbuf,
                                                 int E, int nbuck) {
    __shared__ int hist[512];
    __shared__ int scn[512];     // inclusive scan of hist
    __shared__ int cur[512];     // scatter cursors
    __shared__ int gbase[512];   // reserved global base per bucket
    __shared__ uint sorted[4096];
    int t = threadIdx.x;
    int off = blockIdx.x * 4096;
    int cnt = min(4096, E - off);

    hist[t] = 0; hist[t + 256] = 0;
    __syncthreads();
    for (int i = t; i < cnt; i += 256) {
        int b = dst[off + i] >> 8;
        atomicAdd(&hist[b], 1);
    }
    __syncthreads();
    scn[t] = hist[t]; scn[t + 256] = hist[t + 256];
    __syncthreads();
    for (int d = 1; d < 256; d <<= 1) {
        int u0 = (t >= d) ? scn[t - d] : 0;
        int u1 = (t >= d) ? scn[256 + t - d] : 0;
        __syncthreads();
        if (t >= d) { scn[t] += u0; scn[256 + t] += u1; }
        __syncthreads();
    }
    int tot0 = scn[255];
    scn[256 + t] += tot0;
    __syncthreads();
    cur[t] = (t == 0) ? 0 : scn[t - 1];
    cur[t + 256] = scn[t + 255];
    if (t < nbuck && hist[t] > 0) gbase[t] = atomicAdd(&bcur[t], hist[t]);
    int t2 = t + 256;
    if (t2 < nbuck && hist[t2] > 0) gbase[t2] = atomicAdd(&bcur[t2], hist[t2]);
    __syncthreads();
    for (int i = t; i < cnt; i += 256) {
        int d = dst[off + i];
        int s = src[off + i];
        int b = d >> 8;
        int pos = atomicAdd(&cur[b], 1);
        sorted[pos] = ((uint)(d & 255) << 24) | (uint)s;
    }
    __syncthreads();
    int wid = t >> 6, lane = t & 63;
    for (int b = wid; b < nbuck; b += 4) {
        int n = hist[b];
        if (n == 0) continue;
        int ls = (b == 0) ? 0 : scn[b - 1];
        int gb = gbase[b];
        for (int j = lane; j < n; j += 64)
            pairbuf[gb + j] = sorted[ls + j];
    }
}

// per bucket: derive node degrees (LDS hist) -> rowptr + dinv (coalesced),
// then scatter pairs into LDS csr and flush coalesced.
#define CSR_CAP 5632
__global__ __launch_bounds__(256) void k_csrbuild(const uint* __restrict__ pairbuf,
                                                  const int* __restrict__ bbase,
                                                  int* __restrict__ rowptr,
                                                  float* __restrict__ dinv,
                                                  int* __restrict__ csr,
                                                  int N, int nbuck) {
    __shared__ int lhist[256];
    __shared__ int scn[256];
    __shared__ int lcur[256];
    __shared__ int lcsr[CSR_CAP];
    int b = blockIdx.x;
    int base = b << 8;
    int nn = min(256, N - base);
    int lo = bbase[b], hi = bbase[b + 1];
    int cnt = hi - lo;
    int t = threadIdx.x;
    lhist[t] = 0;
    __syncthreads();
    for (int i = t; i < cnt; i += 256) atomicAdd(&lhist[pairbuf[lo + i] >> 24], 1);
    __syncthreads();
    int mydeg = lhist[t];
    scn[t] = mydeg;
    __syncthreads();
    for (int d = 1; d < 256; d <<= 1) {
        int u = (t >= d) ? scn[t - d] : 0;
        __syncthreads();
        if (t >= d) scn[t] += u;
        __syncthreads();
    }
    int excl = (t == 0) ? 0 : scn[t - 1];
    lcur[t] = excl;
    if (t < nn) {
        rowptr[base + t] = lo + excl;
        dinv[base + t] = rsqrtf((float)(mydeg + 1));  // +1 = self-loop
    }
    if (b == nbuck - 1 && t == 0) rowptr[N] = hi;
    __syncthreads();
    if (cnt <= CSR_CAP) {
        for (int i = t; i < cnt; i += 256) {
            uint p = pairbuf[lo + i];
            int pos = atomicAdd(&lcur[p >> 24], 1);
            lcsr[pos] = (int)(p & 0xFFFFFFu);
        }
        __syncthreads();
        for (int i = t; i < cnt; i += 256) csr[lo + i] = lcsr[i];
    } else {
        // statistical overflow fallback: scatter within this bucket's region
        for (int i = t; i < cnt; i += 256) {
            uint p = pairbuf[lo + i];
            int pos = lo + atomicAdd(&lcur[p >> 24], 1);
            csr[pos] = (int)(p & 0xFFFFFFu);
        }
    }
}

// ---------------- casts ----------------

__global__ void k_cast_bf16(const float* __restrict__ in, ushort* __restrict__ outp, int n4) {
    int i = blockIdx.x * blockDim.x + threadIdx.x;
    if (i < n4) {
        float4 v = ((const float4*)in)[i];
        uint p0 = (uint)bf16rne(v.x) | ((uint)bf16rne(v.y) << 16);
        uint p1 = (uint)bf16rne(v.z) | ((uint)bf16rne(v.w) << 16);
        ((uint2*)outp)[i] = make_uint2(p0, p1);
    }
}

// W[128x128] fp32 -> Wt[n][k] bf16 (transposed)
__global__ void k_castT(const float* __restrict__ W, ushort* __restrict__ Wt) {
    int i = blockIdx.x * 256 + threadIdx.x;  // 16384 total
    int k = i >> 7, n = i & 127;
    Wt[n * 128 + k] = bf16rne(W[k * 128 + n]);
}

// ---------------- MFMA GEMM: C[M x 128](bf16) = (A[M x 128](bf16) @ W) * dinv[row] ----------------

__global__ __launch_bounds__(256) void k_gemm128_mfma(const ushort* __restrict__ A,
                                                      const ushort* __restrict__ Wt,
                                                      const float* __restrict__ dinv,
                                                      ushort* __restrict__ C, int M) {
    int t = threadIdx.x;
    int wave = t >> 6;
    int lane = t & 63;
    int m16 = lane & 15;
    int quad = lane >> 4;
    int rowA = blockIdx.x * 64 + wave * 16 + m16;
    int rA = min(rowA, M - 1);

    f32x4 acc[8];
#pragma unroll
    for (int i = 0; i < 8; i++) acc[i] = (f32x4){0.f, 0.f, 0.f, 0.f};

#pragma unroll
    for (int k0 = 0; k0 < 128; k0 += 32) {
        bf16x8 a = *(const bf16x8*)(A + (size_t)rA * 128 + k0 + quad * 8);
#pragma unroll
        for (int nt = 0; nt < 8; nt++) {
            bf16x8 b = *(const bf16x8*)(Wt + (size_t)(nt * 16 + m16) * 128 + k0 + quad * 8);
            acc[nt] = __builtin_amdgcn_mfma_f32_16x16x32_bf16(a, b, acc[nt], 0, 0, 0);
        }
    }
    int rowBase = blockIdx.x * 64 + wave * 16 + quad * 4;
    float dnv[4];
#pragma unroll
    for (int r = 0; r < 4; r++) dnv[r] = dinv[min(rowBase + r, M - 1)];
#pragma unroll
    for (int nt = 0; nt < 8; nt++) {
        int col = nt * 16 + m16;
#pragma unroll
        for (int r = 0; r < 4; r++) {
            int row = rowBase + r;
            if (row < M) C[(size_t)row * 128 + col] = bf16rne(acc[nt][r] * dnv[r]);
        }
    }
}

// ---------------- GEMM: C[M x 40](bf16) = (A[M x 128](bf16) @ W2[128 x 40](fp32)) * dinv[row] ----------------

__global__ __launch_bounds__(256) void k_gemm40_b(const ushort* __restrict__ A,
                                                  const float* __restrict__ W,
                                                  const float* __restrict__ dinv,
                                                  ushort* __restrict__ C, int M) {
    __shared__ float As[64][132];
    __shared__ float Ws[128][40];
    int t = threadIdx.x;
    int r = t >> 2;
    int c0 = t & 3;
    int row0 = blockIdx.x * 64;

    float* wflat = &Ws[0][0];
#pragma unroll
    for (int f = t; f < 1280; f += 256)
        *(float4*)&wflat[f * 4] = *(const float4*)(W + (size_t)f * 4);
#pragma unroll
    for (int f = t; f < 4096; f += 256) {
        int rr = f >> 6, q = f & 63;
        int row = row0 + rr;
        uint p = 0;
        if (row < M) p = ((const uint*)A)[(size_t)row * 64 + q];
        float a0, a1;
        unpack2(p, a0, a1);
        As[rr][q * 2] = a0;
        As[rr][q * 2 + 1] = a1;
    }
    __syncthreads();

    float acc[10];
#pragma unroll
    for (int j = 0; j < 10; j++) acc[j] = 0.f;
    for (int k = 0; k < 128; k++) {
        float a = As[r][k];
#pragma unroll
        for (int j = 0; j < 10; j++) acc[j] += a * Ws[k][c0 + 4 * j];
    }
    int row = row0 + r;
    if (row < M) {
        float dn = dinv[row];
#pragma unroll
        for (int j = 0; j < 10; j++) C[(size_t)row * 40 + c0 + 4 * j] = bf16rne(acc[j] * dn);
    }
}

// ---------------- aggregation (bf16 pre-scaled features, fp32 accumulate) ----------------

__global__ __launch_bounds__(256) void k_agg128_b(const ushort* __restrict__ g,
                                                  const float* __restrict__ dinv,
                                                  const int* __restrict__ rowptr,
                                                  const int* __restrict__ csr,
                                                  const float* __restrict__ bias,
                                                  ushort* __restrict__ hout,
                                                  int relu, int N) {
    int t = threadIdx.x;
    int grp = t >> 5;
    int l = t & 31;
    int node = blockIdx.x * 8 + grp;
    if (node >= N) return;
    const uint2* g8 = (const uint2*)g;
    float dn = dinv[node];
    float4 acc;
    {
        uint2 p = g8[(size_t)node * 32 + l];
        unpack2(p.x, acc.x, acc.y);
        unpack2(p.y, acc.z, acc.w);
    }
    int e0 = rowptr[node], e1 = rowptr[node + 1];
    int e = e0;
    for (; e + 4 <= e1; e += 4) {
        int s0 = csr[e], s1 = csr[e + 1], s2 = csr[e + 2], s3 = csr[e + 3];
        uint2 p0 = g8[(size_t)s0 * 32 + l];
        uint2 p1 = g8[(size_t)s1 * 32 + l];
        uint2 p2 = g8[(size_t)s2 * 32 + l];
        uint2 p3 = g8[(size_t)s3 * 32 + l];
        float a0, a1, a2, a3;
        unpack2(p0.x, a0, a1); unpack2(p0.y, a2, a3);
        acc.x += a0; acc.y += a1; acc.z += a2; acc.w += a3;
        unpack2(p1.x, a0, a1); unpack2(p1.y, a2, a3);
        acc.x += a0; acc.y += a1; acc.z += a2; acc.w += a3;
        unpack2(p2.x, a0, a1); unpack2(p2.y, a2, a3);
        acc.x += a0; acc.y += a1; acc.z += a2; acc.w += a3;
        unpack2(p3.x, a0, a1); unpack2(p3.y, a2, a3);
        acc.x += a0; acc.y += a1; acc.z += a2; acc.w += a3;
    }
    for (; e < e1; e++) {
        int s = csr[e];
        uint2 p = g8[(size_t)s * 32 + l];
        float a0, a1, a2, a3;
        unpack2(p.x, a0, a1); unpack2(p.y, a2, a3);
        acc.x += a0; acc.y += a1; acc.z += a2; acc.w += a3;
    }
    float4 bb = ((const float4*)bias)[l];
    float4 o;
    o.x = acc.x * dn + bb.x;
    o.y = acc.y * dn + bb.y;
    o.z = acc.z * dn + bb.z;
    o.w = acc.w * dn + bb.w;
    if (relu) {
        o.x = fmaxf(o.x, 0.f); o.y = fmaxf(o.y, 0.f);
        o.z = fmaxf(o.z, 0.f); o.w = fmaxf(o.w, 0.f);
    }
    uint q0 = (uint)bf16rne(o.x) | ((uint)bf16rne(o.y) << 16);
    uint q1 = (uint)bf16rne(o.z) | ((uint)bf16rne(o.w) << 16);
    ((uint2*)hout)[(size_t)node * 32 + l] = make_uint2(q0, q1);
}

__global__ __launch_bounds__(256) void k_agg40_b(const ushort* __restrict__ g3,
                                                 const float* __restrict__ dinv,
                                                 const int* __restrict__ rowptr,
                                                 const int* __restrict__ csr,
                                                 const float* __restrict__ bias,
                                                 float* __restrict__ out, int N) {
    int t = threadIdx.x;
    if (t >= 240) return;
    int grp = t / 20;
    int l = t - grp * 20;
    int node = blockIdx.x * 12 + grp;
    if (node >= N) return;
    const uint* gp = (const uint*)g3;
    float dn = dinv[node];
    float a0, a1;
    unpack2(gp[(size_t)node * 20 + l], a0, a1);
    int e0 = rowptr[node], e1 = rowptr[node + 1];
    int e = e0;
    for (; e + 4 <= e1; e += 4) {
        int s0 = csr[e], s1 = csr[e + 1], s2 = csr[e + 2], s3 = csr[e + 3];
        uint p0 = gp[(size_t)s0 * 20 + l];
        uint p1 = gp[(size_t)s1 * 20 + l];
        uint p2 = gp[(size_t)s2 * 20 + l];
        uint p3 = gp[(size_t)s3 * 20 + l];
        float u, v;
        unpack2(p0, u, v); a0 += u; a1 += v;
        unpack2(p1, u, v); a0 += u; a1 += v;
        unpack2(p2, u, v); a0 += u; a1 += v;
        unpack2(p3, u, v); a0 += u; a1 += v;
    }
    for (; e < e1; e++) {
        int s = csr[e];
        float u, v;
        unpack2(gp[(size_t)s * 20 + l], u, v);
        a0 += u; a1 += v;
    }
    float2 o;
    o.x = a0 * dn + bias[2 * l];
    o.y = a1 * dn + bias[2 * l + 1];
    ((float2*)out)[(size_t)node * 20 + l] = o;
}

// ---------------- launch ----------------

extern "C" void kernel_launch(void* const* d_in, const int* in_sizes, int n_in,
                              void* d_out, int out_size, void* d_ws, size_t ws_size,
                              hipStream_t stream) {
    const float* x  = (const float*)d_in[0];
    const int* eidx = (const int*)d_in[1];
    const float* W1 = (const float*)d_in[2];
    const float* b1 = (const float*)d_in[3];
    const float* Wm = (const float*)d_in[4];
    const float* bm = (const float*)d_in[5];
    const float* W2 = (const float*)d_in[6];
    const float* b2 = (const float*)d_in[7];
    float* out = (float*)d_out;

    int N = in_sizes[0] / 128;
    int E = in_sizes[1] / 2;
    const int* src = eidx;
    const int* dst = eidx + E;
    int nbuck = (N + 255) >> 8;

    char* ws = (char*)d_ws;
    size_t off = 0;
    auto alloc = [&](size_t bytes) -> void* {
        void* p = ws + off;
        off += (bytes + 255) & ~(size_t)255;
        return p;
    };
    float*  dinv    = (float*)alloc((size_t)N * 4);
    int*    rowptr  = (int*)alloc(((size_t)N + 1) * 4);
    int*    csr     = (int*)alloc((size_t)E * 4);
    uint*   pairbuf = (uint*)alloc((size_t)E * 4);
    int*    bcnt    = (int*)alloc(512 * 4);
    int*    bbase   = (int*)alloc(513 * 4);
    int*    bcur    = (int*)alloc(512 * 4);
    ushort* xb      = (ushort*)alloc((size_t)N * 128 * 2);
    ushort* w1t     = (ushort*)alloc(128 * 128 * 2);
    ushort* wmt     = (ushort*)alloc(128 * 128 * 2);
    ushort* gbuf    = (ushort*)alloc((size_t)N * 128 * 2);
    ushort* hbuf    = (ushort*)alloc((size_t)N * 128 * 2);

    // bucketed graph build (no per-node atomics anywhere)
    hipMemsetAsync(bcnt, 0, 512 * 4, stream);
    k_bhist<<<(E + 4095) / 4096, 256, 0, stream>>>(dst, bcnt, E);
    k_bscan<<<1, 512, 0, stream>>>(bcnt, bbase, bcur, nbuck);
    k_binpack<<<(E + 4095) / 4096, 256, 0, stream>>>(src, dst, bcur, pairbuf, E, nbuck);
    k_csrbuild<<<nbuck, 256, 0, stream>>>(pairbuf, bbase, rowptr, dinv, csr, N, nbuck);

    // casts
    int n4 = N * 128 / 4;
    k_cast_bf16<<<(n4 + 255) / 256, 256, 0, stream>>>(x, xb, n4);
    k_castT<<<64, 256, 0, stream>>>(W1, w1t);
    k_castT<<<64, 256, 0, stream>>>(Wm, wmt);

    int gblk = (N + 63) / 64;
    // layer 1
    k_gemm128_mfma<<<gblk, 256, 0, stream>>>(xb, w1t, dinv, gbuf, N);
    k_agg128_b<<<(N + 7) / 8, 256, 0, stream>>>(gbuf, dinv, rowptr, csr, b1, hbuf, 1, N);
    // layer 2
    k_gemm128_mfma<<<gblk, 256, 0, stream>>>(hbuf, wmt, dinv, gbuf, N);
    k_agg128_b<<<(N + 7) / 8, 256, 0, stream>>>(gbuf, dinv, rowptr, csr, bm, hbuf, 1, N);
    // layer 3
    k_gemm40_b<<<(N + 63) / 64, 256, 0, stream>>>(hbuf, W2, dinv, gbuf, N);
    k_agg40_b<<<(N + 11) / 12, 256, 0, stream>>>(gbuf, dinv, rowptr, csr, b2, out, N);
}

// Round 7
// 460.147 us; speedup vs baseline: 2.4679x; 1.0239x over previous
//
#include <hip/hip_runtime.h>
#include <hip/hip_bf16.h>

typedef __attribute__((ext_vector_type(8))) short bf16x8;
typedef __attribute__((ext_vector_type(4))) float f32x4;

__device__ __forceinline__ ushort bf16rne(float f) {
    uint u = __float_as_uint(f);
    return (ushort)((u + 0x7fffu + ((u >> 16) & 1u)) >> 16);
}
__device__ __forceinline__ void unpack2(uint p, float& a, float& b) {
    a = __uint_as_float(p << 16);
    b = __uint_as_float(p & 0xffff0000u);
}

// ---------------- bucketed graph preprocessing ----------------
// bucket = dst >> 8 (256 nodes per bucket), nbuck <= 512. Packed pair:
// (dst&255)<<24 | src  (src < 2^24).

__global__ __launch_bounds__(256) void k_bhist(const int* __restrict__ dst,
                                               int* __restrict__ bcnt, int E) {
    __shared__ int hist[512];
    int t = threadIdx.x;
    hist[t] = 0; hist[t + 256] = 0;
    __syncthreads();
    int off = blockIdx.x * 4096;
    int cnt = min(4096, E - off);
    for (int i = t; i < cnt; i += 256) atomicAdd(&hist[dst[off + i] >> 8], 1);
    __syncthreads();
    if (hist[t]) atomicAdd(&bcnt[t], hist[t]);
    if (hist[t + 256]) atomicAdd(&bcnt[t + 256], hist[t + 256]);
}

__global__ void k_bscan(const int* __restrict__ bcnt, int* __restrict__ bbase,
                        int* __restrict__ bcur, int nbuck) {
    __shared__ int s[512];
    int t = threadIdx.x;  // 512
    s[t] = (t < nbuck) ? bcnt[t] : 0;
    __syncthreads();
    for (int d = 1; d < 512; d <<= 1) {
        int u = (t >= d) ? s[t - d] : 0;
        __syncthreads();
        if (t >= d) s[t] += u;
        __syncthreads();
    }
    int excl = (t == 0) ? 0 : s[t - 1];
    bbase[t] = excl;
    if (t < nbuck) bcur[t] = excl;
    if (t == 511) bbase[512] = s[511];
}

__global__ __launch_bounds__(256) void k_binpack(const int* __restrict__ src,
                                                 const int* __restrict__ dst,
                                                 int* __restrict__ bcur,
                                                 uint* __restrict__ pairbuf,
                                                 int E, int nbuck) {
    __shared__ int hist[512];
    __shared__ int scn[512];
    __shared__ int cur[512];
    __shared__ int gbase[512];
    __shared__ uint sorted[4096];
    int t = threadIdx.x;
    int off = blockIdx.x * 4096;
    int cnt = min(4096, E - off);

    hist[t] = 0; hist[t + 256] = 0;
    __syncthreads();
    for (int i = t; i < cnt; i += 256) {
        int b = dst[off + i] >> 8;
        atomicAdd(&hist[b], 1);
    }
    __syncthreads();
    scn[t] = hist[t]; scn[t + 256] = hist[t + 256];
    __syncthreads();
    for (int d = 1; d < 256; d <<= 1) {
        int u0 = (t >= d) ? scn[t - d] : 0;
        int u1 = (t >= d) ? scn[256 + t - d] : 0;
        __syncthreads();
        if (t >= d) { scn[t] += u0; scn[256 + t] += u1; }
        __syncthreads();
    }
    int tot0 = scn[255];
    scn[256 + t] += tot0;
    __syncthreads();
    cur[t] = (t == 0) ? 0 : scn[t - 1];
    cur[t + 256] = scn[t + 255];
    if (t < nbuck && hist[t] > 0) gbase[t] = atomicAdd(&bcur[t], hist[t]);
    int t2 = t + 256;
    if (t2 < nbuck && hist[t2] > 0) gbase[t2] = atomicAdd(&bcur[t2], hist[t2]);
    __syncthreads();
    for (int i = t; i < cnt; i += 256) {
        int d = dst[off + i];
        int s = src[off + i];
        int b = d >> 8;
        int pos = atomicAdd(&cur[b], 1);
        sorted[pos] = ((uint)(d & 255) << 24) | (uint)s;
    }
    __syncthreads();
    int wid = t >> 6, lane = t & 63;
    for (int b = wid; b < nbuck; b += 4) {
        int n = hist[b];
        if (n == 0) continue;
        int ls = (b == 0) ? 0 : scn[b - 1];
        int gb = gbase[b];
        for (int j = lane; j < n; j += 64)
            pairbuf[gb + j] = sorted[ls + j];
    }
}

#define CSR_CAP 5632
__global__ __launch_bounds__(256) void k_csrbuild(const uint* __restrict__ pairbuf,
                                                  const int* __restrict__ bbase,
                                                  int* __restrict__ rowptr,
                                                  float* __restrict__ dinv,
                                                  int* __restrict__ csr,
                                                  int N, int nbuck) {
    __shared__ int lhist[256];
    __shared__ int scn[256];
    __shared__ int lcur[256];
    __shared__ int lcsr[CSR_CAP];
    int b = blockIdx.x;
    int base = b << 8;
    int nn = min(256, N - base);
    int lo = bbase[b], hi = bbase[b + 1];
    int cnt = hi - lo;
    int t = threadIdx.x;
    lhist[t] = 0;
    __syncthreads();
    for (int i = t; i < cnt; i += 256) atomicAdd(&lhist[pairbuf[lo + i] >> 24], 1);
    __syncthreads();
    int mydeg = lhist[t];
    scn[t] = mydeg;
    __syncthreads();
    for (int d = 1; d < 256; d <<= 1) {
        int u = (t >= d) ? scn[t - d] : 0;
        __syncthreads();
        if (t >= d) scn[t] += u;
        __syncthreads();
    }
    int excl = (t == 0) ? 0 : scn[t - 1];
    lcur[t] = excl;
    if (t < nn) {
        rowptr[base + t] = lo + excl;
        dinv[base + t] = rsqrtf((float)(mydeg + 1));  // +1 = self-loop
    }
    if (b == nbuck - 1 && t == 0) rowptr[N] = hi;
    __syncthreads();
    if (cnt <= CSR_CAP) {
        for (int i = t; i < cnt; i += 256) {
            uint p = pairbuf[lo + i];
            int pos = atomicAdd(&lcur[p >> 24], 1);
            lcsr[pos] = (int)(p & 0xFFFFFFu);
        }
        __syncthreads();
        for (int i = t; i < cnt; i += 256) csr[lo + i] = lcsr[i];
    } else {
        for (int i = t; i < cnt; i += 256) {
            uint p = pairbuf[lo + i];
            int pos = lo + atomicAdd(&lcur[p >> 24], 1);
            csr[pos] = (int)(p & 0xFFFFFFu);
        }
    }
}

// ---------------- casts ----------------

__global__ void k_cast_bf16(const float* __restrict__ in, ushort* __restrict__ outp, int n4) {
    int i = blockIdx.x * blockDim.x + threadIdx.x;
    if (i < n4) {
        float4 v = ((const float4*)in)[i];
        uint p0 = (uint)bf16rne(v.x) | ((uint)bf16rne(v.y) << 16);
        uint p1 = (uint)bf16rne(v.z) | ((uint)bf16rne(v.w) << 16);
        ((uint2*)outp)[i] = make_uint2(p0, p1);
    }
}

__global__ void k_castT(const float* __restrict__ W, ushort* __restrict__ Wt) {
    int i = blockIdx.x * 256 + threadIdx.x;
    int k = i >> 7, n = i & 127;
    Wt[n * 128 + k] = bf16rne(W[k * 128 + n]);
}

// ---------------- MFMA GEMM: C[M x 128](bf16) = (A[M x 128](bf16) @ W) * dinv[row] ----------------

__global__ __launch_bounds__(256) void k_gemm128_mfma(const ushort* __restrict__ A,
                                                      const ushort* __restrict__ Wt,
                                                      const float* __restrict__ dinv,
                                                      ushort* __restrict__ C, int M) {
    int t = threadIdx.x;
    int wave = t >> 6;
    int lane = t & 63;
    int m16 = lane & 15;
    int quad = lane >> 4;
    int rowA = blockIdx.x * 64 + wave * 16 + m16;
    int rA = min(rowA, M - 1);

    f32x4 acc[8];
#pragma unroll
    for (int i = 0; i < 8; i++) acc[i] = (f32x4){0.f, 0.f, 0.f, 0.f};

#pragma unroll
    for (int k0 = 0; k0 < 128; k0 += 32) {
        bf16x8 a = *(const bf16x8*)(A + (size_t)rA * 128 + k0 + quad * 8);
#pragma unroll
        for (int nt = 0; nt < 8; nt++) {
            bf16x8 b = *(const bf16x8*)(Wt + (size_t)(nt * 16 + m16) * 128 + k0 + quad * 8);
            acc[nt] = __builtin_amdgcn_mfma_f32_16x16x32_bf16(a, b, acc[nt], 0, 0, 0);
        }
    }
    int rowBase = blockIdx.x * 64 + wave * 16 + quad * 4;
    float dnv[4];
#pragma unroll
    for (int r = 0; r < 4; r++) dnv[r] = dinv[min(rowBase + r, M - 1)];
#pragma unroll
    for (int nt = 0; nt < 8; nt++) {
        int col = nt * 16 + m16;
#pragma unroll
        for (int r = 0; r < 4; r++) {
            int row = rowBase + r;
            if (row < M) C[(size_t)row * 128 + col] = bf16rne(acc[nt][r] * dnv[r]);
        }
    }
}

// ---------------- GEMM: C[M x 40](bf16) = (A[M x 128](bf16) @ W2[128 x 40](fp32)) * dinv[row] ----------------

__global__ __launch_bounds__(256) void k_gemm40_b(const ushort* __restrict__ A,
                                                  const float* __restrict__ W,
                                                  const float* __restrict__ dinv,
                                                  ushort* __restrict__ C, int M) {
    __shared__ float As[64][132];
    __shared__ float Ws[128][40];
    int t = threadIdx.x;
    int r = t >> 2;
    int c0 = t & 3;
    int row0 = blockIdx.x * 64;

    float* wflat = &Ws[0][0];
#pragma unroll
    for (int f = t; f < 1280; f += 256)
        *(float4*)&wflat[f * 4] = *(const float4*)(W + (size_t)f * 4);
#pragma unroll
    for (int f = t; f < 4096; f += 256) {
        int rr = f >> 6, q = f & 63;
        int row = row0 + rr;
        uint p = 0;
        if (row < M) p = ((const uint*)A)[(size_t)row * 64 + q];
        float a0, a1;
        unpack2(p, a0, a1);
        As[rr][q * 2] = a0;
        As[rr][q * 2 + 1] = a1;
    }
    __syncthreads();

    float acc[10];
#pragma unroll
    for (int j = 0; j < 10; j++) acc[j] = 0.f;
    for (int k = 0; k < 128; k++) {
        float a = As[r][k];
#pragma unroll
        for (int j = 0; j < 10; j++) acc[j] += a * Ws[k][c0 + 4 * j];
    }
    int row = row0 + r;
    if (row < M) {
        float dn = dinv[row];
#pragma unroll
        for (int j = 0; j < 10; j++) C[(size_t)row * 40 + c0 + 4 * j] = bf16rne(acc[j] * dn);
    }
}

// ---------------- aggregation (bf16 pre-scaled features, fp32 accumulate) ----------------
// 16 lanes x uint4 (16 B) per 256-B row; 16 nodes per 256-thread block;
// edge loop unrolled x4 -> 16 rows in flight per wave.

__global__ __launch_bounds__(256) void k_agg128_b(const ushort* __restrict__ g,
                                                  const float* __restrict__ dinv,
                                                  const int* __restrict__ rowptr,
                                                  const int* __restrict__ csr,
                                                  const float* __restrict__ bias,
                                                  ushort* __restrict__ hout,
                                                  int relu, int N) {
    int t = threadIdx.x;
    int grp = t >> 4;
    int l = t & 15;
    int node = blockIdx.x * 16 + grp;
    if (node >= N) return;
    const uint4* g16 = (const uint4*)g;  // 16 uint4 per 128-bf16 row
    float dn = dinv[node];
    float a[8];
    {
        uint4 p = g16[(size_t)node * 16 + l];
        unpack2(p.x, a[0], a[1]); unpack2(p.y, a[2], a[3]);
        unpack2(p.z, a[4], a[5]); unpack2(p.w, a[6], a[7]);
    }
    int e0 = rowptr[node], e1 = rowptr[node + 1];
    int e = e0;
    for (; e + 4 <= e1; e += 4) {
        int s0 = csr[e], s1 = csr[e + 1], s2 = csr[e + 2], s3 = csr[e + 3];
        uint4 p0 = g16[(size_t)s0 * 16 + l];
        uint4 p1 = g16[(size_t)s1 * 16 + l];
        uint4 p2 = g16[(size_t)s2 * 16 + l];
        uint4 p3 = g16[(size_t)s3 * 16 + l];
        float u, v;
        unpack2(p0.x, u, v); a[0] += u; a[1] += v;
        unpack2(p0.y, u, v); a[2] += u; a[3] += v;
        unpack2(p0.z, u, v); a[4] += u; a[5] += v;
        unpack2(p0.w, u, v); a[6] += u; a[7] += v;
        unpack2(p1.x, u, v); a[0] += u; a[1] += v;
        unpack2(p1.y, u, v); a[2] += u; a[3] += v;
        unpack2(p1.z, u, v); a[4] += u; a[5] += v;
        unpack2(p1.w, u, v); a[6] += u; a[7] += v;
        unpack2(p2.x, u, v); a[0] += u; a[1] += v;
        unpack2(p2.y, u, v); a[2] += u; a[3] += v;
        unpack2(p2.z, u, v); a[4] += u; a[5] += v;
        unpack2(p2.w, u, v); a[6] += u; a[7] += v;
        unpack2(p3.x, u, v); a[0] += u; a[1] += v;
        unpack2(p3.y, u, v); a[2] += u; a[3] += v;
        unpack2(p3.z, u, v); a[4] += u; a[5] += v;
        unpack2(p3.w, u, v); a[6] += u; a[7] += v;
    }
    for (; e < e1; e++) {
        int s = csr[e];
        uint4 p = g16[(size_t)s * 16 + l];
        float u, v;
        unpack2(p.x, u, v); a[0] += u; a[1] += v;
        unpack2(p.y, u, v); a[2] += u; a[3] += v;
        unpack2(p.z, u, v); a[4] += u; a[5] += v;
        unpack2(p.w, u, v); a[6] += u; a[7] += v;
    }
    float4 b0 = ((const float4*)bias)[2 * l];
    float4 b1 = ((const float4*)bias)[2 * l + 1];
    float o[8];
    o[0] = a[0] * dn + b0.x; o[1] = a[1] * dn + b0.y;
    o[2] = a[2] * dn + b0.z; o[3] = a[3] * dn + b0.w;
    o[4] = a[4] * dn + b1.x; o[5] = a[5] * dn + b1.y;
    o[6] = a[6] * dn + b1.z; o[7] = a[7] * dn + b1.w;
    if (relu) {
#pragma unroll
        for (int i = 0; i < 8; i++) o[i] = fmaxf(o[i], 0.f);
    }
    uint4 q;
    q.x = (uint)bf16rne(o[0]) | ((uint)bf16rne(o[1]) << 16);
    q.y = (uint)bf16rne(o[2]) | ((uint)bf16rne(o[3]) << 16);
    q.z = (uint)bf16rne(o[4]) | ((uint)bf16rne(o[5]) << 16);
    q.w = (uint)bf16rne(o[6]) | ((uint)bf16rne(o[7]) << 16);
    ((uint4*)hout)[(size_t)node * 16 + l] = q;
}

// 40-bf16 rows (80 B) = 10 lanes x uint2; 25 nodes per block (250 threads); x4 unroll.
__global__ __launch_bounds__(256) void k_agg40_b(const ushort* __restrict__ g3,
                                                 const float* __restrict__ dinv,
                                                 const int* __restrict__ rowptr,
                                                 const int* __restrict__ csr,
                                                 const float* __restrict__ bias,
                                                 float* __restrict__ out, int N) {
    int t = threadIdx.x;
    if (t >= 250) return;
    int grp = t / 10;
    int l = t - grp * 10;
    int node = blockIdx.x * 25 + grp;
    if (node >= N) return;
    const uint2* gp = (const uint2*)g3;  // 10 uint2 per 40-bf16 row
    float dn = dinv[node];
    float a0, a1, a2, a3;
    {
        uint2 p = gp[(size_t)node * 10 + l];
        unpack2(p.x, a0, a1);
        unpack2(p.y, a2, a3);
    }
    int e0 = rowptr[node], e1 = rowptr[node + 1];
    int e = e0;
    for (; e + 4 <= e1; e += 4) {
        int s0 = csr[e], s1 = csr[e + 1], s2 = csr[e + 2], s3 = csr[e + 3];
        uint2 p0 = gp[(size_t)s0 * 10 + l];
        uint2 p1 = gp[(size_t)s1 * 10 + l];
        uint2 p2 = gp[(size_t)s2 * 10 + l];
        uint2 p3 = gp[(size_t)s3 * 10 + l];
        float u, v;
        unpack2(p0.x, u, v); a0 += u; a1 += v;
        unpack2(p0.y, u, v); a2 += u; a3 += v;
        unpack2(p1.x, u, v); a0 += u; a1 += v;
        unpack2(p1.y, u, v); a2 += u; a3 += v;
        unpack2(p2.x, u, v); a0 += u; a1 += v;
        unpack2(p2.y, u, v); a2 += u; a3 += v;
        unpack2(p3.x, u, v); a0 += u; a1 += v;
        unpack2(p3.y, u, v); a2 += u; a3 += v;
    }
    for (; e < e1; e++) {
        int s = csr[e];
        uint2 p = gp[(size_t)s * 10 + l];
        float u, v;
        unpack2(p.x, u, v); a0 += u; a1 += v;
        unpack2(p.y, u, v); a2 += u; a3 += v;
    }
    float4 bb = ((const float4*)bias)[l];
    float4 o;
    o.x = a0 * dn + bb.x;
    o.y = a1 * dn + bb.y;
    o.z = a2 * dn + bb.z;
    o.w = a3 * dn + bb.w;
    ((float4*)out)[(size_t)node * 10 + l] = o;
}

// ---------------- launch ----------------

extern "C" void kernel_launch(void* const* d_in, const int* in_sizes, int n_in,
                              void* d_out, int out_size, void* d_ws, size_t ws_size,
                              hipStream_t stream) {
    const float* x  = (const float*)d_in[0];
    const int* eidx = (const int*)d_in[1];
    const float* W1 = (const float*)d_in[2];
    const float* b1 = (const float*)d_in[3];
    const float* Wm = (const float*)d_in[4];
    const float* bm = (const float*)d_in[5];
    const float* W2 = (const float*)d_in[6];
    const float* b2 = (const float*)d_in[7];
    float* out = (float*)d_out;

    int N = in_sizes[0] / 128;
    int E = in_sizes[1] / 2;
    const int* src = eidx;
    const int* dst = eidx + E;
    int nbuck = (N + 255) >> 8;

    char* ws = (char*)d_ws;
    size_t off = 0;
    auto alloc = [&](size_t bytes) -> void* {
        void* p = ws + off;
        off += (bytes + 255) & ~(size_t)255;
        return p;
    };
    float*  dinv    = (float*)alloc((size_t)N * 4);
    int*    rowptr  = (int*)alloc(((size_t)N + 1) * 4);
    int*    csr     = (int*)alloc((size_t)E * 4);
    uint*   pairbuf = (uint*)alloc((size_t)E * 4);
    int*    bcnt    = (int*)alloc(512 * 4);
    int*    bbase   = (int*)alloc(513 * 4);
    int*    bcur    = (int*)alloc(512 * 4);
    ushort* xb      = (ushort*)alloc((size_t)N * 128 * 2);
    ushort* w1t     = (ushort*)alloc(128 * 128 * 2);
    ushort* wmt     = (ushort*)alloc(128 * 128 * 2);
    ushort* gbuf    = (ushort*)alloc((size_t)N * 128 * 2);
    ushort* hbuf    = (ushort*)alloc((size_t)N * 128 * 2);

    hipMemsetAsync(bcnt, 0, 512 * 4, stream);
    k_bhist<<<(E + 4095) / 4096, 256, 0, stream>>>(dst, bcnt, E);
    k_bscan<<<1, 512, 0, stream>>>(bcnt, bbase, bcur, nbuck);
    k_binpack<<<(E + 4095) / 4096, 256, 0, stream>>>(src, dst, bcur, pairbuf, E, nbuck);
    k_csrbuild<<<nbuck, 256, 0, stream>>>(pairbuf, bbase, rowptr, dinv, csr, N, nbuck);

    int n4 = N * 128 / 4;
    k_cast_bf16<<<(n4 + 255) / 256, 256, 0, stream>>>(x, xb, n4);
    k_castT<<<64, 256, 0, stream>>>(W1, w1t);
    k_castT<<<64, 256, 0, stream>>>(Wm, wmt);

    int gblk = (N + 63) / 64;
    // layer 1
    k_gemm128_mfma<<<gblk, 256, 0, stream>>>(xb, w1t, dinv, gbuf, N);
    k_agg128_b<<<(N + 15) / 16, 256, 0, stream>>>(gbuf, dinv, rowptr, csr, b1, hbuf, 1, N);
    // layer 2
    k_gemm128_mfma<<<gblk, 256, 0, stream>>>(hbuf, wmt, dinv, gbuf, N);
    k_agg128_b<<<(N + 15) / 16, 256, 0, stream>>>(gbuf, dinv, rowptr, csr, bm, hbuf, 1, N);
    // layer 3
    k_gemm40_b<<<(N + 63) / 64, 256, 0, stream>>>(hbuf, W2, dinv, gbuf, N);
    k_agg40_b<<<(N + 24) / 25, 256, 0, stream>>>(gbuf, dinv, rowptr, csr, b2, out, N);
}

// Round 8
// 415.833 us; speedup vs baseline: 2.7308x; 1.1066x over previous
//
#include <hip/hip_runtime.h>
#include <hip/hip_bf16.h>

typedef __attribute__((ext_vector_type(8))) short bf16x8;
typedef __attribute__((ext_vector_type(4))) float f32x4;

__device__ __forceinline__ ushort bf16rne(float f) {
    uint u = __float_as_uint(f);
    return (ushort)((u + 0x7fffu + ((u >> 16) & 1u)) >> 16);
}
__device__ __forceinline__ void unpack2(uint p, float& a, float& b) {
    a = __uint_as_float(p << 16);
    b = __uint_as_float(p & 0xffff0000u);
}

// ---------------- bucketed graph preprocessing ----------------
// bucket = dst >> 8 (256 nodes per bucket), nbuck <= 512. Packed pair:
// (dst&255)<<24 | src  (src < 2^24).

__global__ __launch_bounds__(256) void k_bhist(const int* __restrict__ dst,
                                               int* __restrict__ bcnt, int E) {
    __shared__ int hist[512];
    int t = threadIdx.x;
    hist[t] = 0; hist[t + 256] = 0;
    __syncthreads();
    int off = blockIdx.x * 4096;
    int cnt = min(4096, E - off);
    for (int i = t; i < cnt; i += 256) atomicAdd(&hist[dst[off + i] >> 8], 1);
    __syncthreads();
    if (hist[t]) atomicAdd(&bcnt[t], hist[t]);
    if (hist[t + 256]) atomicAdd(&bcnt[t + 256], hist[t + 256]);
}

__global__ void k_bscan(const int* __restrict__ bcnt, int* __restrict__ bbase,
                        int* __restrict__ bcur, int nbuck) {
    __shared__ int s[512];
    int t = threadIdx.x;  // 512
    s[t] = (t < nbuck) ? bcnt[t] : 0;
    __syncthreads();
    for (int d = 1; d < 512; d <<= 1) {
        int u = (t >= d) ? s[t - d] : 0;
        __syncthreads();
        if (t >= d) s[t] += u;
        __syncthreads();
    }
    int excl = (t == 0) ? 0 : s[t - 1];
    bbase[t] = excl;
    if (t < nbuck) bcur[t] = excl;
    if (t == 511) bbase[512] = s[511];
}

__global__ __launch_bounds__(256) void k_binpack(const int* __restrict__ src,
                                                 const int* __restrict__ dst,
                                                 int* __restrict__ bcur,
                                                 uint* __restrict__ pairbuf,
                                                 int E, int nbuck) {
    __shared__ int hist[512];
    __shared__ int scn[512];
    __shared__ int cur[512];
    __shared__ int gbase[512];
    __shared__ uint sorted[4096];
    int t = threadIdx.x;
    int off = blockIdx.x * 4096;
    int cnt = min(4096, E - off);

    hist[t] = 0; hist[t + 256] = 0;
    __syncthreads();
    for (int i = t; i < cnt; i += 256) {
        int b = dst[off + i] >> 8;
        atomicAdd(&hist[b], 1);
    }
    __syncthreads();
    scn[t] = hist[t]; scn[t + 256] = hist[t + 256];
    __syncthreads();
    for (int d = 1; d < 256; d <<= 1) {
        int u0 = (t >= d) ? scn[t - d] : 0;
        int u1 = (t >= d) ? scn[256 + t - d] : 0;
        __syncthreads();
        if (t >= d) { scn[t] += u0; scn[256 + t] += u1; }
        __syncthreads();
    }
    int tot0 = scn[255];
    scn[256 + t] += tot0;
    __syncthreads();
    cur[t] = (t == 0) ? 0 : scn[t - 1];
    cur[t + 256] = scn[t + 255];
    if (t < nbuck && hist[t] > 0) gbase[t] = atomicAdd(&bcur[t], hist[t]);
    int t2 = t + 256;
    if (t2 < nbuck && hist[t2] > 0) gbase[t2] = atomicAdd(&bcur[t2], hist[t2]);
    __syncthreads();
    for (int i = t; i < cnt; i += 256) {
        int d = dst[off + i];
        int s = src[off + i];
        int b = d >> 8;
        int pos = atomicAdd(&cur[b], 1);
        sorted[pos] = ((uint)(d & 255) << 24) | (uint)s;
    }
    __syncthreads();
    int wid = t >> 6, lane = t & 63;
    for (int b = wid; b < nbuck; b += 4) {
        int n = hist[b];
        if (n == 0) continue;
        int ls = (b == 0) ? 0 : scn[b - 1];
        int gb = gbase[b];
        for (int j = lane; j < n; j += 64)
            pairbuf[gb + j] = sorted[ls + j];
    }
}

#define CSR_CAP 5632
__global__ __launch_bounds__(256) void k_csrbuild(const uint* __restrict__ pairbuf,
                                                  const int* __restrict__ bbase,
                                                  int* __restrict__ rowptr,
                                                  float* __restrict__ dinv,
                                                  int* __restrict__ csr,
                                                  int N, int nbuck) {
    __shared__ int lhist[256];
    __shared__ int scn[256];
    __shared__ int lcur[256];
    __shared__ int lcsr[CSR_CAP];
    int b = blockIdx.x;
    int base = b << 8;
    int nn = min(256, N - base);
    int lo = bbase[b], hi = bbase[b + 1];
    int cnt = hi - lo;
    int t = threadIdx.x;
    lhist[t] = 0;
    __syncthreads();
    for (int i = t; i < cnt; i += 256) atomicAdd(&lhist[pairbuf[lo + i] >> 24], 1);
    __syncthreads();
    int mydeg = lhist[t];
    scn[t] = mydeg;
    __syncthreads();
    for (int d = 1; d < 256; d <<= 1) {
        int u = (t >= d) ? scn[t - d] : 0;
        __syncthreads();
        if (t >= d) scn[t] += u;
        __syncthreads();
    }
    int excl = (t == 0) ? 0 : scn[t - 1];
    lcur[t] = excl;
    if (t < nn) {
        rowptr[base + t] = lo + excl;
        dinv[base + t] = rsqrtf((float)(mydeg + 1));  // +1 = self-loop
    }
    if (b == nbuck - 1 && t == 0) rowptr[N] = hi;
    __syncthreads();
    if (cnt <= CSR_CAP) {
        for (int i = t; i < cnt; i += 256) {
            uint p = pairbuf[lo + i];
            int pos = atomicAdd(&lcur[p >> 24], 1);
            lcsr[pos] = (int)(p & 0xFFFFFFu);
        }
        __syncthreads();
        for (int i = t; i < cnt; i += 256) csr[lo + i] = lcsr[i];
    } else {
        for (int i = t; i < cnt; i += 256) {
            uint p = pairbuf[lo + i];
            int pos = lo + atomicAdd(&lcur[p >> 24], 1);
            csr[pos] = (int)(p & 0xFFFFFFu);
        }
    }
}

// ---------------- weight transpose+cast (one kernel for W1, Wm, W2) ----------------
// w1t/wmt: [128][128] (n-major); w2t: [48][128] zero-padded (40 real cols).

__global__ void k_castT_all(const float* __restrict__ W1, const float* __restrict__ Wm,
                            const float* __restrict__ W2, ushort* __restrict__ w1t,
                            ushort* __restrict__ wmt, ushort* __restrict__ w2t) {
    int b = blockIdx.x;
    int t = threadIdx.x;
    if (b < 64) {
        int i = b * 256 + t; int k = i >> 7, n = i & 127;
        w1t[n * 128 + k] = bf16rne(W1[k * 128 + n]);
    } else if (b < 128) {
        int i = (b - 64) * 256 + t; int k = i >> 7, n = i & 127;
        wmt[n * 128 + k] = bf16rne(Wm[k * 128 + n]);
    } else {
        int i = (b - 128) * 256 + t;  // 0..6143 over [48][128]
        if (i < 6144) {
            int n = i >> 7, k = i & 127;
            w2t[n * 128 + k] = (n < 40) ? bf16rne(W2[k * 40 + n]) : (ushort)0;
        }
    }
}

// ---------------- layer-1 GEMM: C[M x 128](bf16) = (f32 x @ W1) * dinv[row] ----------------
// Reads fp32 x directly (cast kernel fused away).

__global__ __launch_bounds__(256) void k_gemm1(const float* __restrict__ A,
                                               const ushort* __restrict__ Wt,
                                               const float* __restrict__ dinv,
                                               ushort* __restrict__ C, int M) {
    int t = threadIdx.x;
    int wave = t >> 6, lane = t & 63;
    int m16 = lane & 15, quad = lane >> 4;
    int rowA = blockIdx.x * 64 + wave * 16 + m16;
    int rA = min(rowA, M - 1);
    const float4* A4 = (const float4*)A;  // 32 float4 per row

    f32x4 acc[8];
#pragma unroll
    for (int i = 0; i < 8; i++) acc[i] = (f32x4){0.f, 0.f, 0.f, 0.f};

#pragma unroll
    for (int it = 0; it < 4; it++) {
        float4 f0 = A4[(size_t)rA * 32 + 8 * it + 2 * quad];
        float4 f1 = A4[(size_t)rA * 32 + 8 * it + 2 * quad + 1];
        bf16x8 af;
        af[0] = (short)bf16rne(f0.x); af[1] = (short)bf16rne(f0.y);
        af[2] = (short)bf16rne(f0.z); af[3] = (short)bf16rne(f0.w);
        af[4] = (short)bf16rne(f1.x); af[5] = (short)bf16rne(f1.y);
        af[6] = (short)bf16rne(f1.z); af[7] = (short)bf16rne(f1.w);
#pragma unroll
        for (int nt = 0; nt < 8; nt++) {
            bf16x8 bfr = *(const bf16x8*)(Wt + (size_t)(nt * 16 + m16) * 128 + it * 32 + quad * 8);
            acc[nt] = __builtin_amdgcn_mfma_f32_16x16x32_bf16(af, bfr, acc[nt], 0, 0, 0);
        }
    }
    int rowBase = blockIdx.x * 64 + wave * 16 + quad * 4;
    float dnv[4];
#pragma unroll
    for (int r = 0; r < 4; r++) dnv[r] = dinv[min(rowBase + r, M - 1)];
#pragma unroll
    for (int nt = 0; nt < 8; nt++) {
        int col = nt * 16 + m16;
#pragma unroll
        for (int r = 0; r < 4; r++) {
            int row = rowBase + r;
            if (row < M) C[(size_t)row * 128 + col] = bf16rne(acc[nt][r] * dnv[r]);
        }
    }
}

// ---------------- fused agg + GEMM ----------------
// Aggregates pre-scaled bf16 rows of g for 64 nodes/block DIRECTLY INTO MFMA
// A-fragment layout (lane m16 = row, quad -> k-slices {32*it + quad*8}), applies
// bias+relu+bf16 round, then multiplies by Wt and writes pre-scaled output.
// No LDS, no intermediate h buffer.

template <int NT>  // number of 16-col n-tiles in Wt (8 for 128, 3 for 48)
__device__ __forceinline__ void fused_agg_gemm(const ushort* __restrict__ g,
                                               const float* __restrict__ dinv,
                                               const int* __restrict__ rowptr,
                                               const int* __restrict__ csr,
                                               const float* __restrict__ bias,
                                               const ushort* __restrict__ Wt,
                                               ushort* __restrict__ C,
                                               int M, int ccols) {
    int t = threadIdx.x;
    int wave = t >> 6, lane = t & 63;
    int m16 = lane & 15, quad = lane >> 4;
    int node = blockIdx.x * 64 + wave * 16 + m16;
    int nd = min(node, M - 1);
    const uint4* g16 = (const uint4*)g;  // 16 uint4 per 128-bf16 row
    float dn = dinv[nd];

    float a[4][8];
    {
#pragma unroll
        for (int it = 0; it < 4; it++) {
            uint4 p = g16[(size_t)nd * 16 + 4 * it + quad];
            unpack2(p.x, a[it][0], a[it][1]); unpack2(p.y, a[it][2], a[it][3]);
            unpack2(p.z, a[it][4], a[it][5]); unpack2(p.w, a[it][6], a[it][7]);
        }
    }
    int e0 = rowptr[nd], e1 = rowptr[nd + 1];
    int e = e0;
    for (; e + 2 <= e1; e += 2) {
        int s0 = csr[e], s1 = csr[e + 1];
        uint4 p0[4], p1[4];
#pragma unroll
        for (int it = 0; it < 4; it++) p0[it] = g16[(size_t)s0 * 16 + 4 * it + quad];
#pragma unroll
        for (int it = 0; it < 4; it++) p1[it] = g16[(size_t)s1 * 16 + 4 * it + quad];
        float u, v;
#pragma unroll
        for (int it = 0; it < 4; it++) {
            unpack2(p0[it].x, u, v); a[it][0] += u; a[it][1] += v;
            unpack2(p0[it].y, u, v); a[it][2] += u; a[it][3] += v;
            unpack2(p0[it].z, u, v); a[it][4] += u; a[it][5] += v;
            unpack2(p0[it].w, u, v); a[it][6] += u; a[it][7] += v;
            unpack2(p1[it].x, u, v); a[it][0] += u; a[it][1] += v;
            unpack2(p1[it].y, u, v); a[it][2] += u; a[it][3] += v;
            unpack2(p1[it].z, u, v); a[it][4] += u; a[it][5] += v;
            unpack2(p1[it].w, u, v); a[it][6] += u; a[it][7] += v;
        }
    }
    for (; e < e1; e++) {
        int s = csr[e];
        float u, v;
#pragma unroll
        for (int it = 0; it < 4; it++) {
            uint4 p = g16[(size_t)s * 16 + 4 * it + quad];
            unpack2(p.x, u, v); a[it][0] += u; a[it][1] += v;
            unpack2(p.y, u, v); a[it][2] += u; a[it][3] += v;
            unpack2(p.z, u, v); a[it][4] += u; a[it][5] += v;
            unpack2(p.w, u, v); a[it][6] += u; a[it][7] += v;
        }
    }
    // epilogue of agg: h = relu(acc*dn + bias) -> bf16 A-fragments
    const float4* b4 = (const float4*)bias;
    bf16x8 frag[4];
#pragma unroll
    for (int it = 0; it < 4; it++) {
        float4 bb0 = b4[8 * it + 2 * quad];
        float4 bb1 = b4[8 * it + 2 * quad + 1];
        float o0 = fmaxf(a[it][0] * dn + bb0.x, 0.f);
        float o1 = fmaxf(a[it][1] * dn + bb0.y, 0.f);
        float o2 = fmaxf(a[it][2] * dn + bb0.z, 0.f);
        float o3 = fmaxf(a[it][3] * dn + bb0.w, 0.f);
        float o4 = fmaxf(a[it][4] * dn + bb1.x, 0.f);
        float o5 = fmaxf(a[it][5] * dn + bb1.y, 0.f);
        float o6 = fmaxf(a[it][6] * dn + bb1.z, 0.f);
        float o7 = fmaxf(a[it][7] * dn + bb1.w, 0.f);
        frag[it][0] = (short)bf16rne(o0); frag[it][1] = (short)bf16rne(o1);
        frag[it][2] = (short)bf16rne(o2); frag[it][3] = (short)bf16rne(o3);
        frag[it][4] = (short)bf16rne(o4); frag[it][5] = (short)bf16rne(o5);
        frag[it][6] = (short)bf16rne(o6); frag[it][7] = (short)bf16rne(o7);
    }
    // GEMM: h @ W
    f32x4 acc[NT];
#pragma unroll
    for (int i = 0; i < NT; i++) acc[i] = (f32x4){0.f, 0.f, 0.f, 0.f};
#pragma unroll
    for (int it = 0; it < 4; it++) {
#pragma unroll
        for (int nt = 0; nt < NT; nt++) {
            bf16x8 bfr = *(const bf16x8*)(Wt + (size_t)(nt * 16 + m16) * 128 + it * 32 + quad * 8);
            acc[nt] = __builtin_amdgcn_mfma_f32_16x16x32_bf16(frag[it], bfr, acc[nt], 0, 0, 0);
        }
    }
    int rowBase = blockIdx.x * 64 + wave * 16 + quad * 4;
    float dnv[4];
#pragma unroll
    for (int r = 0; r < 4; r++) dnv[r] = dinv[min(rowBase + r, M - 1)];
#pragma unroll
    for (int nt = 0; nt < NT; nt++) {
        int col = nt * 16 + m16;
        if (col >= ccols) continue;
#pragma unroll
        for (int r = 0; r < 4; r++) {
            int row = rowBase + r;
            if (row < M) C[(size_t)row * ccols + col] = bf16rne(acc[nt][r] * dnv[r]);
        }
    }
}

__global__ __launch_bounds__(256) void k_fusedA(const ushort* __restrict__ g,
                                                const float* __restrict__ dinv,
                                                const int* __restrict__ rowptr,
                                                const int* __restrict__ csr,
                                                const float* __restrict__ bias,
                                                const ushort* __restrict__ Wt,
                                                ushort* __restrict__ C, int M) {
    fused_agg_gemm<8>(g, dinv, rowptr, csr, bias, Wt, C, M, 128);
}

__global__ __launch_bounds__(256) void k_fusedB(const ushort* __restrict__ g,
                                                const float* __restrict__ dinv,
                                                const int* __restrict__ rowptr,
                                                const int* __restrict__ csr,
                                                const float* __restrict__ bias,
                                                const ushort* __restrict__ Wt,
                                                ushort* __restrict__ C, int M) {
    fused_agg_gemm<3>(g, dinv, rowptr, csr, bias, Wt, C, M, 40);
}

// ---------------- final aggregation over 40-col rows ----------------
// 40-bf16 rows (80 B) = 10 lanes x uint2; 25 nodes per block; x4 unroll; fp32 out.

__global__ __launch_bounds__(256) void k_agg40_b(const ushort* __restrict__ g3,
                                                 const float* __restrict__ dinv,
                                                 const int* __restrict__ rowptr,
                                                 const int* __restrict__ csr,
                                                 const float* __restrict__ bias,
                                                 float* __restrict__ out, int N) {
    int t = threadIdx.x;
    if (t >= 250) return;
    int grp = t / 10;
    int l = t - grp * 10;
    int node = blockIdx.x * 25 + grp;
    if (node >= N) return;
    const uint2* gp = (const uint2*)g3;  // 10 uint2 per 40-bf16 row
    float dn = dinv[node];
    float a0, a1, a2, a3;
    {
        uint2 p = gp[(size_t)node * 10 + l];
        unpack2(p.x, a0, a1);
        unpack2(p.y, a2, a3);
    }
    int e0 = rowptr[node], e1 = rowptr[node + 1];
    int e = e0;
    for (; e + 4 <= e1; e += 4) {
        int s0 = csr[e], s1 = csr[e + 1], s2 = csr[e + 2], s3 = csr[e + 3];
        uint2 p0 = gp[(size_t)s0 * 10 + l];
        uint2 p1 = gp[(size_t)s1 * 10 + l];
        uint2 p2 = gp[(size_t)s2 * 10 + l];
        uint2 p3 = gp[(size_t)s3 * 10 + l];
        float u, v;
        unpack2(p0.x, u, v); a0 += u; a1 += v;
        unpack2(p0.y, u, v); a2 += u; a3 += v;
        unpack2(p1.x, u, v); a0 += u; a1 += v;
        unpack2(p1.y, u, v); a2 += u; a3 += v;
        unpack2(p2.x, u, v); a0 += u; a1 += v;
        unpack2(p2.y, u, v); a2 += u; a3 += v;
        unpack2(p3.x, u, v); a0 += u; a1 += v;
        unpack2(p3.y, u, v); a2 += u; a3 += v;
    }
    for (; e < e1; e++) {
        int s = csr[e];
        uint2 p = gp[(size_t)s * 10 + l];
        float u, v;
        unpack2(p.x, u, v); a0 += u; a1 += v;
        unpack2(p.y, u, v); a2 += u; a3 += v;
    }
    float4 bb = ((const float4*)bias)[l];
    float4 o;
    o.x = a0 * dn + bb.x;
    o.y = a1 * dn + bb.y;
    o.z = a2 * dn + bb.z;
    o.w = a3 * dn + bb.w;
    ((float4*)out)[(size_t)node * 10 + l] = o;
}

// ---------------- launch ----------------

extern "C" void kernel_launch(void* const* d_in, const int* in_sizes, int n_in,
                              void* d_out, int out_size, void* d_ws, size_t ws_size,
                              hipStream_t stream) {
    const float* x  = (const float*)d_in[0];
    const int* eidx = (const int*)d_in[1];
    const float* W1 = (const float*)d_in[2];
    const float* b1 = (const float*)d_in[3];
    const float* Wm = (const float*)d_in[4];
    const float* bm = (const float*)d_in[5];
    const float* W2 = (const float*)d_in[6];
    const float* b2 = (const float*)d_in[7];
    float* out = (float*)d_out;

    int N = in_sizes[0] / 128;
    int E = in_sizes[1] / 2;
    const int* src = eidx;
    const int* dst = eidx + E;
    int nbuck = (N + 255) >> 8;

    char* ws = (char*)d_ws;
    size_t off = 0;
    auto alloc = [&](size_t bytes) -> void* {
        void* p = ws + off;
        off += (bytes + 255) & ~(size_t)255;
        return p;
    };
    float*  dinv    = (float*)alloc((size_t)N * 4);
    int*    rowptr  = (int*)alloc(((size_t)N + 1) * 4);
    int*    csr     = (int*)alloc((size_t)E * 4);
    uint*   pairbuf = (uint*)alloc((size_t)E * 4);
    int*    bcnt    = (int*)alloc(512 * 4);
    int*    bbase   = (int*)alloc(513 * 4);
    int*    bcur    = (int*)alloc(512 * 4);
    ushort* w1t     = (ushort*)alloc(128 * 128 * 2);
    ushort* wmt     = (ushort*)alloc(128 * 128 * 2);
    ushort* w2t     = (ushort*)alloc(48 * 128 * 2);
    ushort* gbuf    = (ushort*)alloc((size_t)N * 128 * 2);
    ushort* gbuf2   = (ushort*)alloc((size_t)N * 128 * 2);
    ushort* g3      = (ushort*)alloc((size_t)N * 40 * 2);

    hipMemsetAsync(bcnt, 0, 512 * 4, stream);
    k_bhist<<<(E + 4095) / 4096, 256, 0, stream>>>(dst, bcnt, E);
    k_bscan<<<1, 512, 0, stream>>>(bcnt, bbase, bcur, nbuck);
    k_binpack<<<(E + 4095) / 4096, 256, 0, stream>>>(src, dst, bcur, pairbuf, E, nbuck);
    k_csrbuild<<<nbuck, 256, 0, stream>>>(pairbuf, bbase, rowptr, dinv, csr, N, nbuck);
    k_castT_all<<<152, 256, 0, stream>>>(W1, Wm, W2, w1t, wmt, w2t);

    int gblk = (N + 63) / 64;
    // layer 1 GEMM (fp32 in, pre-scaled bf16 out)
    k_gemm1<<<gblk, 256, 0, stream>>>(x, w1t, dinv, gbuf, N);
    // layer-1 agg + layer-2 GEMM fused
    k_fusedA<<<gblk, 256, 0, stream>>>(gbuf, dinv, rowptr, csr, b1, wmt, gbuf2, N);
    // layer-2 agg + layer-3 GEMM fused
    k_fusedB<<<gblk, 256, 0, stream>>>(gbuf2, dinv, rowptr, csr, bm, w2t, g3, N);
    // final aggregation
    k_agg40_b<<<(N + 24) / 25, 256, 0, stream>>>(g3, dinv, rowptr, csr, b2, out, N);
}

// Round 9
// 411.150 us; speedup vs baseline: 2.7619x; 1.0114x over previous
//
#include <hip/hip_runtime.h>
#include <hip/hip_bf16.h>

typedef __attribute__((ext_vector_type(8))) short bf16x8;
typedef __attribute__((ext_vector_type(4))) float f32x4;

__device__ __forceinline__ ushort bf16rne(float f) {
    uint u = __float_as_uint(f);
    return (ushort)((u + 0x7fffu + ((u >> 16) & 1u)) >> 16);
}
__device__ __forceinline__ void unpack2(uint p, float& a, float& b) {
    a = __uint_as_float(p << 16);
    b = __uint_as_float(p & 0xffff0000u);
}

// ---------------- bucketed graph preprocessing ----------------
// bucket = dst >> 8 (256 nodes per bucket), nbuck <= 512. Packed pair:
// (dst&255)<<24 | src  (src < 2^24).

__global__ __launch_bounds__(256) void k_bhist(const int* __restrict__ dst,
                                               int* __restrict__ bcnt, int E) {
    __shared__ int hist[512];
    int t = threadIdx.x;
    hist[t] = 0; hist[t + 256] = 0;
    __syncthreads();
    int off = blockIdx.x * 4096;
    int cnt = min(4096, E - off);
    for (int i = t; i < cnt; i += 256) atomicAdd(&hist[dst[off + i] >> 8], 1);
    __syncthreads();
    if (hist[t]) atomicAdd(&bcnt[t], hist[t]);
    if (hist[t + 256]) atomicAdd(&bcnt[t + 256], hist[t + 256]);
}

__global__ void k_bscan(const int* __restrict__ bcnt, int* __restrict__ bbase,
                        int* __restrict__ bcur, int nbuck) {
    __shared__ int s[512];
    int t = threadIdx.x;  // 512
    s[t] = (t < nbuck) ? bcnt[t] : 0;
    __syncthreads();
    for (int d = 1; d < 512; d <<= 1) {
        int u = (t >= d) ? s[t - d] : 0;
        __syncthreads();
        if (t >= d) s[t] += u;
        __syncthreads();
    }
    int excl = (t == 0) ? 0 : s[t - 1];
    bbase[t] = excl;
    if (t < nbuck) bcur[t] = excl;
    if (t == 511) bbase[512] = s[511];
}

__global__ __launch_bounds__(256) void k_binpack(const int* __restrict__ src,
                                                 const int* __restrict__ dst,
                                                 int* __restrict__ bcur,
                                                 uint* __restrict__ pairbuf,
                                                 int E, int nbuck) {
    __shared__ int hist[512];
    __shared__ int scn[512];
    __shared__ int cur[512];
    __shared__ int gbase[512];
    __shared__ uint sorted[4096];
    int t = threadIdx.x;
    int off = blockIdx.x * 4096;
    int cnt = min(4096, E - off);

    hist[t] = 0; hist[t + 256] = 0;
    __syncthreads();
    for (int i = t; i < cnt; i += 256) {
        int b = dst[off + i] >> 8;
        atomicAdd(&hist[b], 1);
    }
    __syncthreads();
    scn[t] = hist[t]; scn[t + 256] = hist[t + 256];
    __syncthreads();
    for (int d = 1; d < 256; d <<= 1) {
        int u0 = (t >= d) ? scn[t - d] : 0;
        int u1 = (t >= d) ? scn[256 + t - d] : 0;
        __syncthreads();
        if (t >= d) { scn[t] += u0; scn[256 + t] += u1; }
        __syncthreads();
    }
    int tot0 = scn[255];
    scn[256 + t] += tot0;
    __syncthreads();
    cur[t] = (t == 0) ? 0 : scn[t - 1];
    cur[t + 256] = scn[t + 255];
    if (t < nbuck && hist[t] > 0) gbase[t] = atomicAdd(&bcur[t], hist[t]);
    int t2 = t + 256;
    if (t2 < nbuck && hist[t2] > 0) gbase[t2] = atomicAdd(&bcur[t2], hist[t2]);
    __syncthreads();
    for (int i = t; i < cnt; i += 256) {
        int d = dst[off + i];
        int s = src[off + i];
        int b = d >> 8;
        int pos = atomicAdd(&cur[b], 1);
        sorted[pos] = ((uint)(d & 255) << 24) | (uint)s;
    }
    __syncthreads();
    int wid = t >> 6, lane = t & 63;
    for (int b = wid; b < nbuck; b += 4) {
        int n = hist[b];
        if (n == 0) continue;
        int ls = (b == 0) ? 0 : scn[b - 1];
        int gb = gbase[b];
        for (int j = lane; j < n; j += 64)
            pairbuf[gb + j] = sorted[ls + j];
    }
}

#define CSR_CAP 5632
__global__ __launch_bounds__(256) void k_csrbuild(const uint* __restrict__ pairbuf,
                                                  const int* __restrict__ bbase,
                                                  int* __restrict__ rowptr,
                                                  float* __restrict__ dinv,
                                                  int* __restrict__ csr,
                                                  int N, int nbuck) {
    __shared__ int lhist[256];
    __shared__ int scn[256];
    __shared__ int lcur[256];
    __shared__ int lcsr[CSR_CAP];
    int b = blockIdx.x;
    int base = b << 8;
    int nn = min(256, N - base);
    int lo = bbase[b], hi = bbase[b + 1];
    int cnt = hi - lo;
    int t = threadIdx.x;
    lhist[t] = 0;
    __syncthreads();
    for (int i = t; i < cnt; i += 256) atomicAdd(&lhist[pairbuf[lo + i] >> 24], 1);
    __syncthreads();
    int mydeg = lhist[t];
    scn[t] = mydeg;
    __syncthreads();
    for (int d = 1; d < 256; d <<= 1) {
        int u = (t >= d) ? scn[t - d] : 0;
        __syncthreads();
        if (t >= d) scn[t] += u;
        __syncthreads();
    }
    int excl = (t == 0) ? 0 : scn[t - 1];
    lcur[t] = excl;
    if (t < nn) {
        rowptr[base + t] = lo + excl;
        dinv[base + t] = rsqrtf((float)(mydeg + 1));  // +1 = self-loop
    }
    if (b == nbuck - 1 && t == 0) rowptr[N] = hi;
    __syncthreads();
    if (cnt <= CSR_CAP) {
        for (int i = t; i < cnt; i += 256) {
            uint p = pairbuf[lo + i];
            int pos = atomicAdd(&lcur[p >> 24], 1);
            lcsr[pos] = (int)(p & 0xFFFFFFu);
        }
        __syncthreads();
        for (int i = t; i < cnt; i += 256) csr[lo + i] = lcsr[i];
    } else {
        for (int i = t; i < cnt; i += 256) {
            uint p = pairbuf[lo + i];
            int pos = lo + atomicAdd(&lcur[p >> 24], 1);
            csr[pos] = (int)(p & 0xFFFFFFu);
        }
    }
}

// ---------------- weight transpose+cast (one kernel for W1, Wm, W2) ----------------
// w1t/wmt: [128][128] (n-major); w2t: [48][128] zero-padded (40 real cols).

__global__ void k_castT_all(const float* __restrict__ W1, const float* __restrict__ Wm,
                            const float* __restrict__ W2, ushort* __restrict__ w1t,
                            ushort* __restrict__ wmt, ushort* __restrict__ w2t) {
    int b = blockIdx.x;
    int t = threadIdx.x;
    if (b < 64) {
        int i = b * 256 + t; int k = i >> 7, n = i & 127;
        w1t[n * 128 + k] = bf16rne(W1[k * 128 + n]);
    } else if (b < 128) {
        int i = (b - 64) * 256 + t; int k = i >> 7, n = i & 127;
        wmt[n * 128 + k] = bf16rne(Wm[k * 128 + n]);
    } else {
        int i = (b - 128) * 256 + t;  // 0..6143 over [48][128]
        if (i < 6144) {
            int n = i >> 7, k = i & 127;
            w2t[n * 128 + k] = (n < 40) ? bf16rne(W2[k * 40 + n]) : (ushort)0;
        }
    }
}

// ---------------- layer-1 GEMM: C[M x 128](bf16) = (f32 x @ W1) * dinv[row] ----------------

__global__ __launch_bounds__(256) void k_gemm1(const float* __restrict__ A,
                                               const ushort* __restrict__ Wt,
                                               const float* __restrict__ dinv,
                                               ushort* __restrict__ C, int M) {
    int t = threadIdx.x;
    int wave = t >> 6, lane = t & 63;
    int m16 = lane & 15, quad = lane >> 4;
    int rowA = blockIdx.x * 64 + wave * 16 + m16;
    int rA = min(rowA, M - 1);
    const float4* A4 = (const float4*)A;  // 32 float4 per row

    f32x4 acc[8];
#pragma unroll
    for (int i = 0; i < 8; i++) acc[i] = (f32x4){0.f, 0.f, 0.f, 0.f};

#pragma unroll
    for (int it = 0; it < 4; it++) {
        float4 f0 = A4[(size_t)rA * 32 + 8 * it + 2 * quad];
        float4 f1 = A4[(size_t)rA * 32 + 8 * it + 2 * quad + 1];
        bf16x8 af;
        af[0] = (short)bf16rne(f0.x); af[1] = (short)bf16rne(f0.y);
        af[2] = (short)bf16rne(f0.z); af[3] = (short)bf16rne(f0.w);
        af[4] = (short)bf16rne(f1.x); af[5] = (short)bf16rne(f1.y);
        af[6] = (short)bf16rne(f1.z); af[7] = (short)bf16rne(f1.w);
#pragma unroll
        for (int nt = 0; nt < 8; nt++) {
            bf16x8 bfr = *(const bf16x8*)(Wt + (size_t)(nt * 16 + m16) * 128 + it * 32 + quad * 8);
            acc[nt] = __builtin_amdgcn_mfma_f32_16x16x32_bf16(af, bfr, acc[nt], 0, 0, 0);
        }
    }
    int rowBase = blockIdx.x * 64 + wave * 16 + quad * 4;
    float dnv[4];
#pragma unroll
    for (int r = 0; r < 4; r++) dnv[r] = dinv[min(rowBase + r, M - 1)];
#pragma unroll
    for (int nt = 0; nt < 8; nt++) {
        int col = nt * 16 + m16;
#pragma unroll
        for (int r = 0; r < 4; r++) {
            int row = rowBase + r;
            if (row < M) C[(size_t)row * 128 + col] = bf16rne(acc[nt][r] * dnv[r]);
        }
    }
}

// ---------------- fused agg + GEMM (v2: cooperative gather + LDS staging) ----------------
// Agg phase: 16 groups x 16 lanes; each group aggregates 4 nodes sequentially
// with the R7 coalesced pattern (16 lanes x uint4 = one 256B row per load inst,
// x4 edge unroll). Epilogue (bias+relu+bf16) lands in a padded LDS tile
// [64][136] (pad -> 2-way ds_read conflict = free). GEMM phase: standard
// 4-wave MFMA from LDS A-fragments, output pre-scaled by dinv[row].

template <int NT>  // n-tiles in Wt (8 -> 128 cols, 3 -> 48 cols)
__device__ __forceinline__ void fused_agg_gemm(const ushort* __restrict__ g,
                                               const float* __restrict__ dinv,
                                               const int* __restrict__ rowptr,
                                               const int* __restrict__ csr,
                                               const float* __restrict__ bias,
                                               const ushort* __restrict__ Wt,
                                               ushort* __restrict__ C,
                                               int M, int ccols) {
    __shared__ ushort hs[64][136];
    int t = threadIdx.x;
    int grp = t >> 4;   // 0..15
    int l = t & 15;
    const uint4* g16 = (const uint4*)g;  // 16 uint4 per 128-bf16 row
    float4 bb0 = ((const float4*)bias)[2 * l];
    float4 bb1 = ((const float4*)bias)[2 * l + 1];

#pragma unroll
    for (int q = 0; q < 4; q++) {
        int node = blockIdx.x * 64 + grp * 4 + q;
        int nd = min(node, M - 1);
        float dn = dinv[nd];
        float a[8];
        {
            uint4 p = g16[(size_t)nd * 16 + l];
            unpack2(p.x, a[0], a[1]); unpack2(p.y, a[2], a[3]);
            unpack2(p.z, a[4], a[5]); unpack2(p.w, a[6], a[7]);
        }
        int e0 = rowptr[nd], e1 = rowptr[nd + 1];
        int e = e0;
        for (; e + 4 <= e1; e += 4) {
            int s0 = csr[e], s1 = csr[e + 1], s2 = csr[e + 2], s3 = csr[e + 3];
            uint4 p0 = g16[(size_t)s0 * 16 + l];
            uint4 p1 = g16[(size_t)s1 * 16 + l];
            uint4 p2 = g16[(size_t)s2 * 16 + l];
            uint4 p3 = g16[(size_t)s3 * 16 + l];
            float u, v;
            unpack2(p0.x, u, v); a[0] += u; a[1] += v;
            unpack2(p0.y, u, v); a[2] += u; a[3] += v;
            unpack2(p0.z, u, v); a[4] += u; a[5] += v;
            unpack2(p0.w, u, v); a[6] += u; a[7] += v;
            unpack2(p1.x, u, v); a[0] += u; a[1] += v;
            unpack2(p1.y, u, v); a[2] += u; a[3] += v;
            unpack2(p1.z, u, v); a[4] += u; a[5] += v;
            unpack2(p1.w, u, v); a[6] += u; a[7] += v;
            unpack2(p2.x, u, v); a[0] += u; a[1] += v;
            unpack2(p2.y, u, v); a[2] += u; a[3] += v;
            unpack2(p2.z, u, v); a[4] += u; a[5] += v;
            unpack2(p2.w, u, v); a[6] += u; a[7] += v;
            unpack2(p3.x, u, v); a[0] += u; a[1] += v;
            unpack2(p3.y, u, v); a[2] += u; a[3] += v;
            unpack2(p3.z, u, v); a[4] += u; a[5] += v;
            unpack2(p3.w, u, v); a[6] += u; a[7] += v;
        }
        for (; e < e1; e++) {
            int s = csr[e];
            uint4 p = g16[(size_t)s * 16 + l];
            float u, v;
            unpack2(p.x, u, v); a[0] += u; a[1] += v;
            unpack2(p.y, u, v); a[2] += u; a[3] += v;
            unpack2(p.z, u, v); a[4] += u; a[5] += v;
            unpack2(p.w, u, v); a[6] += u; a[7] += v;
        }
        float o0 = fmaxf(a[0] * dn + bb0.x, 0.f);
        float o1 = fmaxf(a[1] * dn + bb0.y, 0.f);
        float o2 = fmaxf(a[2] * dn + bb0.z, 0.f);
        float o3 = fmaxf(a[3] * dn + bb0.w, 0.f);
        float o4 = fmaxf(a[4] * dn + bb1.x, 0.f);
        float o5 = fmaxf(a[5] * dn + bb1.y, 0.f);
        float o6 = fmaxf(a[6] * dn + bb1.z, 0.f);
        float o7 = fmaxf(a[7] * dn + bb1.w, 0.f);
        uint4 qv;
        qv.x = (uint)bf16rne(o0) | ((uint)bf16rne(o1) << 16);
        qv.y = (uint)bf16rne(o2) | ((uint)bf16rne(o3) << 16);
        qv.z = (uint)bf16rne(o4) | ((uint)bf16rne(o5) << 16);
        qv.w = (uint)bf16rne(o6) | ((uint)bf16rne(o7) << 16);
        *(uint4*)&hs[grp * 4 + q][l * 8] = qv;
    }
    __syncthreads();

    // GEMM from LDS
    int wave = t >> 6, lane = t & 63;
    int m16 = lane & 15, quad = lane >> 4;
    f32x4 acc[NT];
#pragma unroll
    for (int i = 0; i < NT; i++) acc[i] = (f32x4){0.f, 0.f, 0.f, 0.f};
#pragma unroll
    for (int it = 0; it < 4; it++) {
        bf16x8 af = *(const bf16x8*)&hs[wave * 16 + m16][it * 32 + quad * 8];
#pragma unroll
        for (int nt = 0; nt < NT; nt++) {
            bf16x8 bfr = *(const bf16x8*)(Wt + (size_t)(nt * 16 + m16) * 128 + it * 32 + quad * 8);
            acc[nt] = __builtin_amdgcn_mfma_f32_16x16x32_bf16(af, bfr, acc[nt], 0, 0, 0);
        }
    }
    int rowBase = blockIdx.x * 64 + wave * 16 + quad * 4;
    float dnv[4];
#pragma unroll
    for (int r = 0; r < 4; r++) dnv[r] = dinv[min(rowBase + r, M - 1)];
#pragma unroll
    for (int nt = 0; nt < NT; nt++) {
        int col = nt * 16 + m16;
        if (col >= ccols) continue;
#pragma unroll
        for (int r = 0; r < 4; r++) {
            int row = rowBase + r;
            if (row < M) C[(size_t)row * ccols + col] = bf16rne(acc[nt][r] * dnv[r]);
        }
    }
}

__global__ __launch_bounds__(256) void k_fusedA(const ushort* __restrict__ g,
                                                const float* __restrict__ dinv,
                                                const int* __restrict__ rowptr,
                                                const int* __restrict__ csr,
                                                const float* __restrict__ bias,
                                                const ushort* __restrict__ Wt,
                                                ushort* __restrict__ C, int M) {
    fused_agg_gemm<8>(g, dinv, rowptr, csr, bias, Wt, C, M, 128);
}

__global__ __launch_bounds__(256) void k_fusedB(const ushort* __restrict__ g,
                                                const float* __restrict__ dinv,
                                                const int* __restrict__ rowptr,
                                                const int* __restrict__ csr,
                                                const float* __restrict__ bias,
                                                const ushort* __restrict__ Wt,
                                                ushort* __restrict__ C, int M) {
    fused_agg_gemm<3>(g, dinv, rowptr, csr, bias, Wt, C, M, 40);
}

// ---------------- final aggregation over 40-col rows ----------------
// 40-bf16 rows (80 B) = 10 lanes x uint2; 25 nodes per block; x4 unroll; fp32 out.

__global__ __launch_bounds__(256) void k_agg40_b(const ushort* __restrict__ g3,
                                                 const float* __restrict__ dinv,
                                                 const int* __restrict__ rowptr,
                                                 const int* __restrict__ csr,
                                                 const float* __restrict__ bias,
                                                 float* __restrict__ out, int N) {
    int t = threadIdx.x;
    if (t >= 250) return;
    int grp = t / 10;
    int l = t - grp * 10;
    int node = blockIdx.x * 25 + grp;
    if (node >= N) return;
    const uint2* gp = (const uint2*)g3;  // 10 uint2 per 40-bf16 row
    float dn = dinv[node];
    float a0, a1, a2, a3;
    {
        uint2 p = gp[(size_t)node * 10 + l];
        unpack2(p.x, a0, a1);
        unpack2(p.y, a2, a3);
    }
    int e0 = rowptr[node], e1 = rowptr[node + 1];
    int e = e0;
    for (; e + 4 <= e1; e += 4) {
        int s0 = csr[e], s1 = csr[e + 1], s2 = csr[e + 2], s3 = csr[e + 3];
        uint2 p0 = gp[(size_t)s0 * 10 + l];
        uint2 p1 = gp[(size_t)s1 * 10 + l];
        uint2 p2 = gp[(size_t)s2 * 10 + l];
        uint2 p3 = gp[(size_t)s3 * 10 + l];
        float u, v;
        unpack2(p0.x, u, v); a0 += u; a1 += v;
        unpack2(p0.y, u, v); a2 += u; a3 += v;
        unpack2(p1.x, u, v); a0 += u; a1 += v;
        unpack2(p1.y, u, v); a2 += u; a3 += v;
        unpack2(p2.x, u, v); a0 += u; a1 += v;
        unpack2(p2.y, u, v); a2 += u; a3 += v;
        unpack2(p3.x, u, v); a0 += u; a1 += v;
        unpack2(p3.y, u, v); a2 += u; a3 += v;
    }
    for (; e < e1; e++) {
        int s = csr[e];
        uint2 p = gp[(size_t)s * 10 + l];
        float u, v;
        unpack2(p.x, u, v); a0 += u; a1 += v;
        unpack2(p.y, u, v); a2 += u; a3 += v;
    }
    float4 bb = ((const float4*)bias)[l];
    float4 o;
    o.x = a0 * dn + bb.x;
    o.y = a1 * dn + bb.y;
    o.z = a2 * dn + bb.z;
    o.w = a3 * dn + bb.w;
    ((float4*)out)[(size_t)node * 10 + l] = o;
}

// ---------------- launch ----------------

extern "C" void kernel_launch(void* const* d_in, const int* in_sizes, int n_in,
                              void* d_out, int out_size, void* d_ws, size_t ws_size,
                              hipStream_t stream) {
    const float* x  = (const float*)d_in[0];
    const int* eidx = (const int*)d_in[1];
    const float* W1 = (const float*)d_in[2];
    const float* b1 = (const float*)d_in[3];
    const float* Wm = (const float*)d_in[4];
    const float* bm = (const float*)d_in[5];
    const float* W2 = (const float*)d_in[6];
    const float* b2 = (const float*)d_in[7];
    float* out = (float*)d_out;

    int N = in_sizes[0] / 128;
    int E = in_sizes[1] / 2;
    const int* src = eidx;
    const int* dst = eidx + E;
    int nbuck = (N + 255) >> 8;

    char* ws = (char*)d_ws;
    size_t off = 0;
    auto alloc = [&](size_t bytes) -> void* {
        void* p = ws + off;
        off += (bytes + 255) & ~(size_t)255;
        return p;
    };
    float*  dinv    = (float*)alloc((size_t)N * 4);
    int*    rowptr  = (int*)alloc(((size_t)N + 1) * 4);
    int*    csr     = (int*)alloc((size_t)E * 4);
    uint*   pairbuf = (uint*)alloc((size_t)E * 4);
    int*    bcnt    = (int*)alloc(512 * 4);
    int*    bbase   = (int*)alloc(513 * 4);
    int*    bcur    = (int*)alloc(512 * 4);
    ushort* w1t     = (ushort*)alloc(128 * 128 * 2);
    ushort* wmt     = (ushort*)alloc(128 * 128 * 2);
    ushort* w2t     = (ushort*)alloc(48 * 128 * 2);
    ushort* gbuf    = (ushort*)alloc((size_t)N * 128 * 2);
    ushort* gbuf2   = (ushort*)alloc((size_t)N * 128 * 2);
    ushort* g3      = (ushort*)alloc((size_t)N * 40 * 2);

    hipMemsetAsync(bcnt, 0, 512 * 4, stream);
    k_bhist<<<(E + 4095) / 4096, 256, 0, stream>>>(dst, bcnt, E);
    k_bscan<<<1, 512, 0, stream>>>(bcnt, bbase, bcur, nbuck);
    k_binpack<<<(E + 4095) / 4096, 256, 0, stream>>>(src, dst, bcur, pairbuf, E, nbuck);
    k_csrbuild<<<nbuck, 256, 0, stream>>>(pairbuf, bbase, rowptr, dinv, csr, N, nbuck);
    k_castT_all<<<152, 256, 0, stream>>>(W1, Wm, W2, w1t, wmt, w2t);

    int gblk = (N + 63) / 64;
    // layer 1 GEMM (fp32 in, pre-scaled bf16 out)
    k_gemm1<<<gblk, 256, 0, stream>>>(x, w1t, dinv, gbuf, N);
    // layer-1 agg + layer-2 GEMM fused
    k_fusedA<<<gblk, 256, 0, stream>>>(gbuf, dinv, rowptr, csr, b1, wmt, gbuf2, N);
    // layer-2 agg + layer-3 GEMM fused
    k_fusedB<<<gblk, 256, 0, stream>>>(gbuf2, dinv, rowptr, csr, bm, w2t, g3, N);
    // final aggregation
    k_agg40_b<<<(N + 24) / 25, 256, 0, stream>>>(g3, dinv, rowptr, csr, b2, out, N);
}

// Round 10
// 383.108 us; speedup vs baseline: 2.9641x; 1.0732x over previous
//
#include <hip/hip_runtime.h>
#include <hip/hip_bf16.h>

typedef __attribute__((ext_vector_type(8))) short bf16x8;
typedef __attribute__((ext_vector_type(4))) float f32x4;

__device__ __forceinline__ ushort bf16rne(float f) {
    uint u = __float_as_uint(f);
    return (ushort)((u + 0x7fffu + ((u >> 16) & 1u)) >> 16);
}
__device__ __forceinline__ void unpack2(uint p, float& a, float& b) {
    a = __uint_as_float(p << 16);
    b = __uint_as_float(p & 0xffff0000u);
}

// ---------------- bucketed graph preprocessing ----------------
// bucket = dst >> 8 (256 nodes per bucket), nbuck <= 512. Packed pair:
// (dst&255)<<24 | src  (src < 2^24).

__global__ __launch_bounds__(256) void k_bhist(const int* __restrict__ dst,
                                               int* __restrict__ bcnt, int E) {
    __shared__ int hist[512];
    int t = threadIdx.x;
    hist[t] = 0; hist[t + 256] = 0;
    __syncthreads();
    int off = blockIdx.x * 4096;
    int cnt = min(4096, E - off);
    for (int i = t; i < cnt; i += 256) atomicAdd(&hist[dst[off + i] >> 8], 1);
    __syncthreads();
    if (hist[t]) atomicAdd(&bcnt[t], hist[t]);
    if (hist[t + 256]) atomicAdd(&bcnt[t + 256], hist[t + 256]);
}

__global__ void k_bscan(const int* __restrict__ bcnt, int* __restrict__ bbase,
                        int* __restrict__ bcur, int nbuck) {
    __shared__ int s[512];
    int t = threadIdx.x;  // 512
    s[t] = (t < nbuck) ? bcnt[t] : 0;
    __syncthreads();
    for (int d = 1; d < 512; d <<= 1) {
        int u = (t >= d) ? s[t - d] : 0;
        __syncthreads();
        if (t >= d) s[t] += u;
        __syncthreads();
    }
    int excl = (t == 0) ? 0 : s[t - 1];
    bbase[t] = excl;
    if (t < nbuck) bcur[t] = excl;
    if (t == 511) bbase[512] = s[511];
}

__global__ __launch_bounds__(256) void k_binpack(const int* __restrict__ src,
                                                 const int* __restrict__ dst,
                                                 int* __restrict__ bcur,
                                                 uint* __restrict__ pairbuf,
                                                 int E, int nbuck) {
    __shared__ int hist[512];
    __shared__ int scn[512];
    __shared__ int cur[512];
    __shared__ int gbase[512];
    __shared__ uint sorted[4096];
    int t = threadIdx.x;
    int off = blockIdx.x * 4096;
    int cnt = min(4096, E - off);

    hist[t] = 0; hist[t + 256] = 0;
    __syncthreads();
    for (int i = t; i < cnt; i += 256) {
        int b = dst[off + i] >> 8;
        atomicAdd(&hist[b], 1);
    }
    __syncthreads();
    scn[t] = hist[t]; scn[t + 256] = hist[t + 256];
    __syncthreads();
    for (int d = 1; d < 256; d <<= 1) {
        int u0 = (t >= d) ? scn[t - d] : 0;
        int u1 = (t >= d) ? scn[256 + t - d] : 0;
        __syncthreads();
        if (t >= d) { scn[t] += u0; scn[256 + t] += u1; }
        __syncthreads();
    }
    int tot0 = scn[255];
    scn[256 + t] += tot0;
    __syncthreads();
    cur[t] = (t == 0) ? 0 : scn[t - 1];
    cur[t + 256] = scn[t + 255];
    if (t < nbuck && hist[t] > 0) gbase[t] = atomicAdd(&bcur[t], hist[t]);
    int t2 = t + 256;
    if (t2 < nbuck && hist[t2] > 0) gbase[t2] = atomicAdd(&bcur[t2], hist[t2]);
    __syncthreads();
    for (int i = t; i < cnt; i += 256) {
        int d = dst[off + i];
        int s = src[off + i];
        int b = d >> 8;
        int pos = atomicAdd(&cur[b], 1);
        sorted[pos] = ((uint)(d & 255) << 24) | (uint)s;
    }
    __syncthreads();
    int wid = t >> 6, lane = t & 63;
    for (int b = wid; b < nbuck; b += 4) {
        int n = hist[b];
        if (n == 0) continue;
        int ls = (b == 0) ? 0 : scn[b - 1];
        int gb = gbase[b];
        for (int j = lane; j < n; j += 64)
            pairbuf[gb + j] = sorted[ls + j];
    }
}

#define CSR_CAP 5632
__global__ __launch_bounds__(256) void k_csrbuild(const uint* __restrict__ pairbuf,
                                                  const int* __restrict__ bbase,
                                                  int* __restrict__ rowptr,
                                                  float* __restrict__ dinv,
                                                  int* __restrict__ csr,
                                                  int N, int nbuck) {
    __shared__ int lhist[256];
    __shared__ int scn[256];
    __shared__ int lcur[256];
    __shared__ int lcsr[CSR_CAP];
    int b = blockIdx.x;
    int base = b << 8;
    int nn = min(256, N - base);
    int lo = bbase[b], hi = bbase[b + 1];
    int cnt = hi - lo;
    int t = threadIdx.x;
    lhist[t] = 0;
    __syncthreads();
    for (int i = t; i < cnt; i += 256) atomicAdd(&lhist[pairbuf[lo + i] >> 24], 1);
    __syncthreads();
    int mydeg = lhist[t];
    scn[t] = mydeg;
    __syncthreads();
    for (int d = 1; d < 256; d <<= 1) {
        int u = (t >= d) ? scn[t - d] : 0;
        __syncthreads();
        if (t >= d) scn[t] += u;
        __syncthreads();
    }
    int excl = (t == 0) ? 0 : scn[t - 1];
    lcur[t] = excl;
    if (t < nn) {
        rowptr[base + t] = lo + excl;
        dinv[base + t] = rsqrtf((float)(mydeg + 1));  // +1 = self-loop
    }
    if (b == nbuck - 1 && t == 0) rowptr[N] = hi;
    __syncthreads();
    if (cnt <= CSR_CAP) {
        for (int i = t; i < cnt; i += 256) {
            uint p = pairbuf[lo + i];
            int pos = atomicAdd(&lcur[p >> 24], 1);
            lcsr[pos] = (int)(p & 0xFFFFFFu);
        }
        __syncthreads();
        for (int i = t; i < cnt; i += 256) csr[lo + i] = lcsr[i];
    } else {
        for (int i = t; i < cnt; i += 256) {
            uint p = pairbuf[lo + i];
            int pos = lo + atomicAdd(&lcur[p >> 24], 1);
            csr[pos] = (int)(p & 0xFFFFFFu);
        }
    }
}

// ---------------- weight transpose+cast (one kernel for W1, Wm, W2) ----------------
// w1t/wmt: [128][128] (n-major); w2t: [48][128] zero-padded (40 real cols).

__global__ void k_castT_all(const float* __restrict__ W1, const float* __restrict__ Wm,
                            const float* __restrict__ W2, ushort* __restrict__ w1t,
                            ushort* __restrict__ wmt, ushort* __restrict__ w2t) {
    int b = blockIdx.x;
    int t = threadIdx.x;
    if (b < 64) {
        int i = b * 256 + t; int k = i >> 7, n = i & 127;
        w1t[n * 128 + k] = bf16rne(W1[k * 128 + n]);
    } else if (b < 128) {
        int i = (b - 64) * 256 + t; int k = i >> 7, n = i & 127;
        wmt[n * 128 + k] = bf16rne(Wm[k * 128 + n]);
    } else {
        int i = (b - 128) * 256 + t;  // 0..6143 over [48][128]
        if (i < 6144) {
            int n = i >> 7, k = i & 127;
            w2t[n * 128 + k] = (n < 40) ? bf16rne(W2[k * 40 + n]) : (ushort)0;
        }
    }
}

// ---------------- layer-1 GEMM: C[M x 128](bf16) = (f32 x @ W1) * dinv[row] ----------------

__global__ __launch_bounds__(256) void k_gemm1(const float* __restrict__ A,
                                               const ushort* __restrict__ Wt,
                                               const float* __restrict__ dinv,
                                               ushort* __restrict__ C, int M) {
    int t = threadIdx.x;
    int wave = t >> 6, lane = t & 63;
    int m16 = lane & 15, quad = lane >> 4;
    int rowA = blockIdx.x * 64 + wave * 16 + m16;
    int rA = min(rowA, M - 1);
    const float4* A4 = (const float4*)A;  // 32 float4 per row

    f32x4 acc[8];
#pragma unroll
    for (int i = 0; i < 8; i++) acc[i] = (f32x4){0.f, 0.f, 0.f, 0.f};

#pragma unroll
    for (int it = 0; it < 4; it++) {
        float4 f0 = A4[(size_t)rA * 32 + 8 * it + 2 * quad];
        float4 f1 = A4[(size_t)rA * 32 + 8 * it + 2 * quad + 1];
        bf16x8 af;
        af[0] = (short)bf16rne(f0.x); af[1] = (short)bf16rne(f0.y);
        af[2] = (short)bf16rne(f0.z); af[3] = (short)bf16rne(f0.w);
        af[4] = (short)bf16rne(f1.x); af[5] = (short)bf16rne(f1.y);
        af[6] = (short)bf16rne(f1.z); af[7] = (short)bf16rne(f1.w);
#pragma unroll
        for (int nt = 0; nt < 8; nt++) {
            bf16x8 bfr = *(const bf16x8*)(Wt + (size_t)(nt * 16 + m16) * 128 + it * 32 + quad * 8);
            acc[nt] = __builtin_amdgcn_mfma_f32_16x16x32_bf16(af, bfr, acc[nt], 0, 0, 0);
        }
    }
    int rowBase = blockIdx.x * 64 + wave * 16 + quad * 4;
    float dnv[4];
#pragma unroll
    for (int r = 0; r < 4; r++) dnv[r] = dinv[min(rowBase + r, M - 1)];
#pragma unroll
    for (int nt = 0; nt < 8; nt++) {
        int col = nt * 16 + m16;
#pragma unroll
        for (int r = 0; r < 4; r++) {
            int row = rowBase + r;
            if (row < M) C[(size_t)row * 128 + col] = bf16rne(acc[nt][r] * dnv[r]);
        }
    }
}

// ---------------- fused agg + GEMM (v3: 32-row tile for occupancy) ----------------
// Agg: 16 groups x 16 lanes, each group 2 nodes serially (R7 coalesced gather:
// 16 lanes x uint4 = one 256B row per load, x4 edge unroll) -> padded LDS
// [32][136]. GEMM: 4 waves = 2 row-halves x 2 n-tile-halves over the 32-row
// tile. Grid = N/32 -> ~12 blocks/CU offered, full wave residency.

template <int NT>  // total n-tiles in Wt (8 -> 128 cols, 3 -> 48/40 cols)
__device__ __forceinline__ void fused_agg_gemm(const ushort* __restrict__ g,
                                               const float* __restrict__ dinv,
                                               const int* __restrict__ rowptr,
                                               const int* __restrict__ csr,
                                               const float* __restrict__ bias,
                                               const ushort* __restrict__ Wt,
                                               ushort* __restrict__ C,
                                               int M, int ccols) {
    __shared__ ushort hs[32][136];
    int t = threadIdx.x;
    int grp = t >> 4;   // 0..15
    int l = t & 15;
    const uint4* g16 = (const uint4*)g;  // 16 uint4 per 128-bf16 row
    float4 bb0 = ((const float4*)bias)[2 * l];
    float4 bb1 = ((const float4*)bias)[2 * l + 1];

#pragma unroll
    for (int q = 0; q < 2; q++) {
        int node = blockIdx.x * 32 + grp * 2 + q;
        int nd = min(node, M - 1);
        float dn = dinv[nd];
        float a[8];
        {
            uint4 p = g16[(size_t)nd * 16 + l];
            unpack2(p.x, a[0], a[1]); unpack2(p.y, a[2], a[3]);
            unpack2(p.z, a[4], a[5]); unpack2(p.w, a[6], a[7]);
        }
        int e0 = rowptr[nd], e1 = rowptr[nd + 1];
        int e = e0;
        for (; e + 4 <= e1; e += 4) {
            int s0 = csr[e], s1 = csr[e + 1], s2 = csr[e + 2], s3 = csr[e + 3];
            uint4 p0 = g16[(size_t)s0 * 16 + l];
            uint4 p1 = g16[(size_t)s1 * 16 + l];
            uint4 p2 = g16[(size_t)s2 * 16 + l];
            uint4 p3 = g16[(size_t)s3 * 16 + l];
            float u, v;
            unpack2(p0.x, u, v); a[0] += u; a[1] += v;
            unpack2(p0.y, u, v); a[2] += u; a[3] += v;
            unpack2(p0.z, u, v); a[4] += u; a[5] += v;
            unpack2(p0.w, u, v); a[6] += u; a[7] += v;
            unpack2(p1.x, u, v); a[0] += u; a[1] += v;
            unpack2(p1.y, u, v); a[2] += u; a[3] += v;
            unpack2(p1.z, u, v); a[4] += u; a[5] += v;
            unpack2(p1.w, u, v); a[6] += u; a[7] += v;
            unpack2(p2.x, u, v); a[0] += u; a[1] += v;
            unpack2(p2.y, u, v); a[2] += u; a[3] += v;
            unpack2(p2.z, u, v); a[4] += u; a[5] += v;
            unpack2(p2.w, u, v); a[6] += u; a[7] += v;
            unpack2(p3.x, u, v); a[0] += u; a[1] += v;
            unpack2(p3.y, u, v); a[2] += u; a[3] += v;
            unpack2(p3.z, u, v); a[4] += u; a[5] += v;
            unpack2(p3.w, u, v); a[6] += u; a[7] += v;
        }
        for (; e < e1; e++) {
            int s = csr[e];
            uint4 p = g16[(size_t)s * 16 + l];
            float u, v;
            unpack2(p.x, u, v); a[0] += u; a[1] += v;
            unpack2(p.y, u, v); a[2] += u; a[3] += v;
            unpack2(p.z, u, v); a[4] += u; a[5] += v;
            unpack2(p.w, u, v); a[6] += u; a[7] += v;
        }
        float o0 = fmaxf(a[0] * dn + bb0.x, 0.f);
        float o1 = fmaxf(a[1] * dn + bb0.y, 0.f);
        float o2 = fmaxf(a[2] * dn + bb0.z, 0.f);
        float o3 = fmaxf(a[3] * dn + bb0.w, 0.f);
        float o4 = fmaxf(a[4] * dn + bb1.x, 0.f);
        float o5 = fmaxf(a[5] * dn + bb1.y, 0.f);
        float o6 = fmaxf(a[6] * dn + bb1.z, 0.f);
        float o7 = fmaxf(a[7] * dn + bb1.w, 0.f);
        uint4 qv;
        qv.x = (uint)bf16rne(o0) | ((uint)bf16rne(o1) << 16);
        qv.y = (uint)bf16rne(o2) | ((uint)bf16rne(o3) << 16);
        qv.z = (uint)bf16rne(o4) | ((uint)bf16rne(o5) << 16);
        qv.w = (uint)bf16rne(o6) | ((uint)bf16rne(o7) << 16);
        *(uint4*)&hs[grp * 2 + q][l * 8] = qv;
    }
    __syncthreads();

    // GEMM from LDS: 4 waves = 2 row-halves x 2 n-tile-halves
    int wave = t >> 6, lane = t & 63;
    int m16 = lane & 15, quad = lane >> 4;
    int rowHalf = wave & 1;
    int ntHalf = wave >> 1;
    constexpr int NTH = (NT + 1) / 2;          // tiles in first half
    int ntStart = ntHalf * NTH;
    int ntEnd = ntHalf ? NT : NTH;

    f32x4 acc[NTH];
#pragma unroll
    for (int i = 0; i < NTH; i++) acc[i] = (f32x4){0.f, 0.f, 0.f, 0.f};
#pragma unroll
    for (int it = 0; it < 4; it++) {
        bf16x8 af = *(const bf16x8*)&hs[rowHalf * 16 + m16][it * 32 + quad * 8];
        for (int nt = ntStart; nt < ntEnd; nt++) {
            bf16x8 bfr = *(const bf16x8*)(Wt + (size_t)(nt * 16 + m16) * 128 + it * 32 + quad * 8);
            acc[nt - ntStart] = __builtin_amdgcn_mfma_f32_16x16x32_bf16(af, bfr, acc[nt - ntStart], 0, 0, 0);
        }
    }
    int rowBase = blockIdx.x * 32 + rowHalf * 16 + quad * 4;
    float dnv[4];
#pragma unroll
    for (int r = 0; r < 4; r++) dnv[r] = dinv[min(rowBase + r, M - 1)];
    for (int nt = ntStart; nt < ntEnd; nt++) {
        int col = nt * 16 + m16;
        if (col >= ccols) continue;
#pragma unroll
        for (int r = 0; r < 4; r++) {
            int row = rowBase + r;
            if (row < M) C[(size_t)row * ccols + col] = bf16rne(acc[nt - ntStart][r] * dnv[r]);
        }
    }
}

__global__ __launch_bounds__(256) void k_fusedA(const ushort* __restrict__ g,
                                                const float* __restrict__ dinv,
                                                const int* __restrict__ rowptr,
                                                const int* __restrict__ csr,
                                                const float* __restrict__ bias,
                                                const ushort* __restrict__ Wt,
                                                ushort* __restrict__ C, int M) {
    fused_agg_gemm<8>(g, dinv, rowptr, csr, bias, Wt, C, M, 128);
}

__global__ __launch_bounds__(256) void k_fusedB(const ushort* __restrict__ g,
                                                const float* __restrict__ dinv,
                                                const int* __restrict__ rowptr,
                                                const int* __restrict__ csr,
                                                const float* __restrict__ bias,
                                                const ushort* __restrict__ Wt,
                                                ushort* __restrict__ C, int M) {
    fused_agg_gemm<3>(g, dinv, rowptr, csr, bias, Wt, C, M, 40);
}

// ---------------- final aggregation over 40-col rows ----------------
// 40-bf16 rows (80 B) = 10 lanes x uint2; 25 nodes per block; x4 unroll; fp32 out.

__global__ __launch_bounds__(256) void k_agg40_b(const ushort* __restrict__ g3,
                                                 const float* __restrict__ dinv,
                                                 const int* __restrict__ rowptr,
                                                 const int* __restrict__ csr,
                                                 const float* __restrict__ bias,
                                                 float* __restrict__ out, int N) {
    int t = threadIdx.x;
    if (t >= 250) return;
    int grp = t / 10;
    int l = t - grp * 10;
    int node = blockIdx.x * 25 + grp;
    if (node >= N) return;
    const uint2* gp = (const uint2*)g3;  // 10 uint2 per 40-bf16 row
    float dn = dinv[node];
    float a0, a1, a2, a3;
    {
        uint2 p = gp[(size_t)node * 10 + l];
        unpack2(p.x, a0, a1);
        unpack2(p.y, a2, a3);
    }
    int e0 = rowptr[node], e1 = rowptr[node + 1];
    int e = e0;
    for (; e + 4 <= e1; e += 4) {
        int s0 = csr[e], s1 = csr[e + 1], s2 = csr[e + 2], s3 = csr[e + 3];
        uint2 p0 = gp[(size_t)s0 * 10 + l];
        uint2 p1 = gp[(size_t)s1 * 10 + l];
        uint2 p2 = gp[(size_t)s2 * 10 + l];
        uint2 p3 = gp[(size_t)s3 * 10 + l];
        float u, v;
        unpack2(p0.x, u, v); a0 += u; a1 += v;
        unpack2(p0.y, u, v); a2 += u; a3 += v;
        unpack2(p1.x, u, v); a0 += u; a1 += v;
        unpack2(p1.y, u, v); a2 += u; a3 += v;
        unpack2(p2.x, u, v); a0 += u; a1 += v;
        unpack2(p2.y, u, v); a2 += u; a3 += v;
        unpack2(p3.x, u, v); a0 += u; a1 += v;
        unpack2(p3.y, u, v); a2 += u; a3 += v;
    }
    for (; e < e1; e++) {
        int s = csr[e];
        uint2 p = gp[(size_t)s * 10 + l];
        float u, v;
        unpack2(p.x, u, v); a0 += u; a1 += v;
        unpack2(p.y, u, v); a2 += u; a3 += v;
    }
    float4 bb = ((const float4*)bias)[l];
    float4 o;
    o.x = a0 * dn + bb.x;
    o.y = a1 * dn + bb.y;
    o.z = a2 * dn + bb.z;
    o.w = a3 * dn + bb.w;
    ((float4*)out)[(size_t)node * 10 + l] = o;
}

// ---------------- launch ----------------

extern "C" void kernel_launch(void* const* d_in, const int* in_sizes, int n_in,
                              void* d_out, int out_size, void* d_ws, size_t ws_size,
                              hipStream_t stream) {
    const float* x  = (const float*)d_in[0];
    const int* eidx = (const int*)d_in[1];
    const float* W1 = (const float*)d_in[2];
    const float* b1 = (const float*)d_in[3];
    const float* Wm = (const float*)d_in[4];
    const float* bm = (const float*)d_in[5];
    const float* W2 = (const float*)d_in[6];
    const float* b2 = (const float*)d_in[7];
    float* out = (float*)d_out;

    int N = in_sizes[0] / 128;
    int E = in_sizes[1] / 2;
    const int* src = eidx;
    const int* dst = eidx + E;
    int nbuck = (N + 255) >> 8;

    char* ws = (char*)d_ws;
    size_t off = 0;
    auto alloc = [&](size_t bytes) -> void* {
        void* p = ws + off;
        off += (bytes + 255) & ~(size_t)255;
        return p;
    };
    float*  dinv    = (float*)alloc((size_t)N * 4);
    int*    rowptr  = (int*)alloc(((size_t)N + 1) * 4);
    int*    csr     = (int*)alloc((size_t)E * 4);
    uint*   pairbuf = (uint*)alloc((size_t)E * 4);
    int*    bcnt    = (int*)alloc(512 * 4);
    int*    bbase   = (int*)alloc(513 * 4);
    int*    bcur    = (int*)alloc(512 * 4);
    ushort* w1t     = (ushort*)alloc(128 * 128 * 2);
    ushort* wmt     = (ushort*)alloc(128 * 128 * 2);
    ushort* w2t     = (ushort*)alloc(48 * 128 * 2);
    ushort* gbuf    = (ushort*)alloc((size_t)N * 128 * 2);
    ushort* gbuf2   = (ushort*)alloc((size_t)N * 128 * 2);
    ushort* g3      = (ushort*)alloc((size_t)N * 40 * 2);

    hipMemsetAsync(bcnt, 0, 512 * 4, stream);
    k_bhist<<<(E + 4095) / 4096, 256, 0, stream>>>(dst, bcnt, E);
    k_bscan<<<1, 512, 0, stream>>>(bcnt, bbase, bcur, nbuck);
    k_binpack<<<(E + 4095) / 4096, 256, 0, stream>>>(src, dst, bcur, pairbuf, E, nbuck);
    k_csrbuild<<<nbuck, 256, 0, stream>>>(pairbuf, bbase, rowptr, dinv, csr, N, nbuck);
    k_castT_all<<<152, 256, 0, stream>>>(W1, Wm, W2, w1t, wmt, w2t);

    int gblk64 = (N + 63) / 64;
    int gblk32 = (N + 31) / 32;
    // layer 1 GEMM (fp32 in, pre-scaled bf16 out)
    k_gemm1<<<gblk64, 256, 0, stream>>>(x, w1t, dinv, gbuf, N);
    // layer-1 agg + layer-2 GEMM fused
    k_fusedA<<<gblk32, 256, 0, stream>>>(gbuf, dinv, rowptr, csr, b1, wmt, gbuf2, N);
    // layer-2 agg + layer-3 GEMM fused
    k_fusedB<<<gblk32, 256, 0, stream>>>(gbuf2, dinv, rowptr, csr, bm, w2t, g3, N);
    // final aggregation
    k_agg40_b<<<(N + 24) / 25, 256, 0, stream>>>(g3, dinv, rowptr, csr, b2, out, N);
}